// Round 12
// baseline (263.601 us; speedup 1.0000x reference)
//
#include <hip/hip_runtime.h>

// ---------------------------------------------------------------------------
// GNNLoss. N=2048, C=512, D=128, K_POOL=1024, T=0.07, NEG=-10.
// Round 12: R8 base (227us) + full-K hop kernel with block-local fused
// epilogue (64x32 tiles, 256 blocks, no split-K partials, no reduce_hop).
// Tag path reverted to R8 mm+combine (R11 fusion was 64-block-starved).
// 16 dispatches. No cross-WG sync primitives (R6/R10: ~30us each on 8-XCD).
// ---------------------------------------------------------------------------

#define TINV (1.0f / 0.07f)

using short8 = __attribute__((ext_vector_type(8))) short;
using f32x4  = __attribute__((ext_vector_type(4))) float;

__device__ __forceinline__ unsigned short f2bf(float f) {
    unsigned u = __float_as_uint(f);
    u += 0x7fff + ((u >> 16) & 1);
    return (unsigned short)(u >> 16);
}

// ---------------- fp32 64x64 tile core -------------------------------------
template<bool BT>
__device__ __forceinline__ void mm_tile(const float* __restrict__ A, int lda,
                                        const float* __restrict__ B, int ldb,
                                        int i0, int j0, int k0, int k1,
                                        float (&acc)[4][4],
                                        float (&As)[16][68], float (&Bs)[16][68])
{
    const int tid = threadIdx.x;
    const int tx = tid & 15;
    const int ty = tid >> 4;
    const int lr = tid >> 2;
    const int lc = (tid & 3) * 4;
    for (int k = k0; k < k1; k += 16) {
        float4 av = *(const float4*)(A + (size_t)(i0 + lr) * lda + (k + lc));
        As[lc + 0][lr] = av.x; As[lc + 1][lr] = av.y;
        As[lc + 2][lr] = av.z; As[lc + 3][lr] = av.w;
        if (BT) {
            float4 bv = *(const float4*)(B + (size_t)(j0 + lr) * ldb + (k + lc));
            Bs[lc + 0][lr] = bv.x; Bs[lc + 1][lr] = bv.y;
            Bs[lc + 2][lr] = bv.z; Bs[lc + 3][lr] = bv.w;
        } else {
            const int n = tid & 63;
            const int kb = tid >> 6;
#pragma unroll
            for (int it = 0; it < 4; ++it)
                Bs[kb * 4 + it][n] = B[(size_t)(k + kb * 4 + it) * ldb + (j0 + n)];
        }
        __syncthreads();
#pragma unroll
        for (int kk = 0; kk < 16; ++kk) {
            float a[4], b[4];
#pragma unroll
            for (int u = 0; u < 4; ++u) a[u] = As[kk][ty * 4 + u];
#pragma unroll
            for (int v = 0; v < 4; ++v) b[v] = Bs[kk][tx * 4 + v];
#pragma unroll
            for (int u = 0; u < 4; ++u)
#pragma unroll
                for (int v = 0; v < 4; ++v)
                    acc[u][v] = fmaf(a[u], b[v], acc[u][v]);
        }
        __syncthreads();
    }
}

// ---------------- launch 1: embed GEMM + setup roles ----------------------
__launch_bounds__(256)
__global__ void k_setup_embed(const float* __restrict__ fs, const float* __restrict__ ft,
                              const float* __restrict__ W, float* __restrict__ part,
                              size_t zstr, int* __restrict__ zwords, int zcount,
                              float* __restrict__ out,
                              const float* __restrict__ Wg, const float* __restrict__ Wp,
                              unsigned short* __restrict__ Wtall)
{
    __shared__ float As[16][68];
    __shared__ float Bs[16][68];
    const int b = blockIdx.x;
    const int tid = threadIdx.x;
    if (b < 512) {
        const int z = b & 3;
        const int by = (b >> 2) & 63;
        const int bx = b >> 8;
        const float* A = (by < 32) ? ft : fs;
        const int i0 = (by & 31) * 64;
        const int j0 = bx * 64;
        float acc[4][4] = {};
        mm_tile<false>(A, 512, W, 128, i0, j0, z * 128, z * 128 + 128, acc, As, Bs);
        const int tx = tid & 15, ty = tid >> 4;
        float* dst = part + (size_t)z * zstr;
#pragma unroll
        for (int u = 0; u < 4; ++u) {
            const size_t ri = (size_t)(by * 64 + ty * 4 + u) * 128 + j0 + tx * 4;
#pragma unroll
            for (int v = 0; v < 4; ++v) dst[ri + v] = acc[u][v];
        }
    } else if (b < 561) {
        const int i = (b - 512) * 256 + tid;
        if (i < zcount) zwords[i] = 0;
        if (b == 512 && tid == 0) out[0] = 0.0f;
    } else {
        const int e0 = (b - 561) * 2048 + tid;
#pragma unroll
        for (int it = 0; it < 8; ++it) {
            const int e = e0 + it * 256;
            const int c = e >> 14;
            const int rem = e & 16383;
            const int n = rem >> 7, k = rem & 127;
            const float* src = (c < 3) ? (Wg + (size_t)c * 16384)
                                       : (Wp + (size_t)(c - 3) * 16384);
            Wtall[e] = f2bf(src[(size_t)k * 128 + n]);
        }
    }
}

// ---------------- fused gram + threshold + pack ----------------------------
__launch_bounds__(256)
__global__ void k_gram_fused(const float* __restrict__ f_e,
                             unsigned short* __restrict__ A01,
                             unsigned long long* __restrict__ bits,
                             int* __restrict__ deg)
{
    __shared__ float As[16][68];
    __shared__ float Bs[16][68];
    __shared__ unsigned char nib[64][16];
    __shared__ unsigned char nibT[64][16];
    __shared__ unsigned long long chk[64];
    __shared__ unsigned long long chkT[64];
    const int b = blockIdx.x;
    int by = (int)((sqrtf(8.0f * b + 1.0f) - 1.0f) * 0.5f);
    while ((by + 1) * (by + 2) / 2 <= b) ++by;
    while (by * (by + 1) / 2 > b) --by;
    const int bx = b - by * (by + 1) / 2;
    const int i0 = by * 64, j0 = bx * 64;
    float acc[4][4] = {};
    mm_tile<true>(f_e, 128, f_e, 128, i0, j0, 0, 128, acc, As, Bs);
    const int tid = threadIdx.x;
    const int tx = tid & 15, ty = tid >> 4;
    unsigned pb = 0;
#pragma unroll
    for (int u = 0; u < 4; ++u)
#pragma unroll
        for (int v = 0; v < 4; ++v) {
            bool pred = (acc[u][v] > 0.0f) || (i0 + ty * 4 + u == j0 + tx * 4 + v);
            pb |= (unsigned)pred << (u * 4 + v);
        }
#pragma unroll
    for (int u = 0; u < 4; ++u) nib[ty * 4 + u][tx] = (pb >> (4 * u)) & 15;
#pragma unroll
    for (int v = 0; v < 4; ++v) {
        unsigned nt = 0;
#pragma unroll
        for (int u = 0; u < 4; ++u) nt |= ((pb >> (u * 4 + v)) & 1u) << u;
        nibT[tx * 4 + v][ty] = nt;
    }
    __syncthreads();
    if (tid < 64) {
        unsigned long long c = 0;
#pragma unroll
        for (int t = 0; t < 16; ++t) c |= (unsigned long long)nib[tid][t] << (4 * t);
        chk[tid] = c;
        bits[(size_t)(i0 + tid) * 32 + (j0 >> 6)] = c;
        atomicAdd(&deg[i0 + tid], __popcll(c));
    } else if (tid < 128 && bx != by) {
        const int r = tid - 64;
        unsigned long long c = 0;
#pragma unroll
        for (int t = 0; t < 16; ++t) c |= (unsigned long long)nibT[r][t] << (4 * t);
        chkT[r] = c;
        bits[(size_t)(j0 + r) * 32 + (i0 >> 6)] = c;
        atomicAdd(&deg[j0 + r], __popcll(c));
    }
    __syncthreads();
#pragma unroll
    for (int it = 0; it < 16; ++it) {
        const int row = it * 4 + (tid >> 6);
        const int col = tid & 63;
        A01[(size_t)(i0 + row) * 2048 + j0 + col] =
            ((chk[row] >> col) & 1) ? (unsigned short)0x3F80 : (unsigned short)0;
        if (bx != by)
            A01[(size_t)(j0 + row) * 2048 + i0 + col] =
                ((chkT[row] >> col) & 1) ? (unsigned short)0x3F80 : (unsigned short)0;
    }
}

// ---------------- full-K hop GEMM + fused dinv epilogue --------------------
// sum[i][n] = sum_k A[i][k]*B[n][k] (bf16). Block: 64 rows x 32 cols, full K.
// hb[(branch*M+i)][n&127] = bf16(sum*dinv[i]); xt[n*M+i] = bf16(sum*dinv^2).
// grid (8, M/64). No partials, no cross-block deps.
__launch_bounds__(256)
__global__ void k_hop(const unsigned short* __restrict__ A, int lda,
                      const unsigned short* __restrict__ B, int ldb,
                      int M, int K, const float* __restrict__ dinv,
                      unsigned short* __restrict__ hb,
                      unsigned short* __restrict__ xt)
{
    __shared__ unsigned short As[64][40];
    __shared__ unsigned short Bs[32][40];
    __shared__ float T[64][33];
    const int tid = threadIdx.x;
    const int i0 = blockIdx.y * 64;
    const int j0 = blockIdx.x * 32;
    const int w = tid >> 6;
    const int lane = tid & 63;
    const int m = lane & 15;
    const int q = lane >> 4;
    f32x4 acc[2];
#pragma unroll
    for (int t = 0; t < 2; ++t)
#pragma unroll
        for (int r = 0; r < 4; ++r) acc[t][r] = 0.0f;

    const int ar = tid >> 2;        // 0..63
    const int ac = (tid & 3) * 8;
    for (int k = 0; k < K; k += 32) {
        *(ulonglong2*)&As[ar][ac] =
            *(const ulonglong2*)(A + (size_t)(i0 + ar) * lda + k + ac);
        if (tid < 128) {
            const int br = tid >> 2;      // 0..31
            const int bc = (tid & 3) * 8;
            *(ulonglong2*)&Bs[br][bc] =
                *(const ulonglong2*)(B + (size_t)(j0 + br) * ldb + k + bc);
        }
        __syncthreads();
        short8 a = *(const short8*)&As[w * 16 + m][q * 8];
#pragma unroll
        for (int nt = 0; nt < 2; ++nt) {
            short8 b = *(const short8*)&Bs[nt * 16 + m][q * 8];
            acc[nt] = __builtin_amdgcn_mfma_f32_16x16x32_bf16(a, b, acc[nt], 0, 0, 0);
        }
        __syncthreads();
    }
    // stash raw sums
#pragma unroll
    for (int nt = 0; nt < 2; ++nt)
#pragma unroll
        for (int r = 0; r < 4; ++r)
            T[w * 16 + q * 4 + r][nt * 16 + m] = acc[nt][r];
    __syncthreads();
    // hb: one row per 4 threads, 8 cols each
    {
        const int r = tid >> 2;
        const int c0 = (tid & 3) * 8;
        const float d = dinv[i0 + r];
        unsigned short o[8];
#pragma unroll
        for (int c = 0; c < 8; ++c) o[c] = f2bf(T[r][c0 + c] * d);
        const int branch = (j0 >= 128) ? M : 0;
        *(ulonglong2*)&hb[(size_t)(branch + i0 + r) * 128 + (j0 & 127) + c0] =
            *(ulonglong2*)o;
    }
    if (xt) {
        const int c = tid >> 3;         // 0..31
        const int r0 = (tid & 7) * 8;
        unsigned short o[8];
#pragma unroll
        for (int rr = 0; rr < 8; ++rr) {
            const float d = dinv[i0 + r0 + rr];
            o[rr] = f2bf(T[r0 + rr][c] * d * d);
        }
        *(ulonglong2*)&xt[(size_t)(j0 + c) * M + i0 + r0] = *(ulonglong2*)o;
    }
}

// ---------------- universal bf16 MFMA GEMM (tag linears) -------------------
__launch_bounds__(256)
__global__ void mm_bf16(const unsigned short* __restrict__ A, int lda, size_t aZ,
                        const unsigned short* __restrict__ B, int ldb, size_t bZ,
                        float* __restrict__ C, int ldc, size_t cZ,
                        int Kc, int kZ)
{
    __shared__ unsigned short As[64][40];
    __shared__ unsigned short Bs[128][40];
    const int tid = threadIdx.x;
    const int bz = blockIdx.z;
    const int i0 = blockIdx.y * 64;
    const int j0 = blockIdx.x * 128;
    const int k0 = bz * kZ;
    const unsigned short* Ab = A + (size_t)bz * aZ;
    const unsigned short* Bb = B + (size_t)bz * bZ;
    float* Cb = C + (size_t)bz * cZ;
    const int w = tid >> 6;
    const int lane = tid & 63;
    const int m = lane & 15;
    const int q = lane >> 4;
    f32x4 acc[8];
#pragma unroll
    for (int t = 0; t < 8; ++t)
#pragma unroll
        for (int r = 0; r < 4; ++r) acc[t][r] = 0.0f;

    const int ar = tid >> 2;
    const int ac = (tid & 3) * 8;
    for (int ks = 0; ks < Kc; ks += 32) {
        const int k = k0 + ks;
        *(ulonglong2*)&As[ar][ac] =
            *(const ulonglong2*)(Ab + (size_t)(i0 + ar) * lda + k + ac);
        *(ulonglong2*)&Bs[ar][ac] =
            *(const ulonglong2*)(Bb + (size_t)(j0 + ar) * ldb + k + ac);
        *(ulonglong2*)&Bs[ar + 64][ac] =
            *(const ulonglong2*)(Bb + (size_t)(j0 + ar + 64) * ldb + k + ac);
        __syncthreads();
        short8 a = *(const short8*)&As[w * 16 + m][q * 8];
#pragma unroll
        for (int nt = 0; nt < 8; ++nt) {
            short8 b = *(const short8*)&Bs[nt * 16 + m][q * 8];
            acc[nt] = __builtin_amdgcn_mfma_f32_16x16x32_bf16(a, b, acc[nt], 0, 0, 0);
        }
        __syncthreads();
    }
#pragma unroll
    for (int nt = 0; nt < 8; ++nt) {
        const int col = j0 + nt * 16 + m;
#pragma unroll
        for (int r = 0; r < 4; ++r) {
            const int row = i0 + w * 16 + q * 4 + r;
            Cb[(size_t)row * ldc + col] = acc[nt][r];
        }
    }
}

// ---------------- combine partials + bias + l2norm (+ optional score) ------
__global__ void combine_norm(const float* __restrict__ part, int nz, size_t zstr,
                             const float* __restrict__ bias,
                             float* __restrict__ f32out,
                             unsigned short* __restrict__ bf16out,
                             const float* __restrict__ Wp, const float* __restrict__ bp,
                             float* __restrict__ scores)
{
    const int row = blockIdx.x;
    const int tid = threadIdx.x;                 // 128
    float v = bias[tid];
    for (int z = 0; z < nz; ++z) v += part[(size_t)z * zstr + (size_t)row * 128 + tid];
    __shared__ float red[128];
    red[tid] = v * v;
    __syncthreads();
    for (int s = 64; s > 0; s >>= 1) {
        if (tid < s) red[tid] += red[tid + s];
        __syncthreads();
    }
    const float o = v * (1.0f / sqrtf(red[0]));
    if (f32out)  f32out[(size_t)row * 128 + tid] = o;
    if (bf16out) bf16out[(size_t)row * 128 + tid] = f2bf(o);
    if (scores && row < 2048) {
        __syncthreads();
        red[tid] = o * Wp[tid];
        __syncthreads();
        for (int s = 64; s > 0; s >>= 1) {
            if (tid < s) red[tid] += red[tid + s];
            __syncthreads();
        }
        if (tid == 0) scores[row] = 1.0f / (1.0f + expf(-(red[0] + bp[0])));
    }
}

// ------------- Xt1[n][i] = f_e[(branch)i][n&127] / sqrt(deg[i]) ------------
__global__ void make_xt(const float* __restrict__ f_e, const int* __restrict__ deg,
                        unsigned short* __restrict__ xt, float* __restrict__ dinv)
{
    __shared__ float T[32][33];
    const int b = blockIdx.x;                    // 512 = 8 x 64
    const int bx = b & 7, by = b >> 3;
    const int tid = threadIdx.x;                 // 256
    const int iloc = tid >> 3, nq = (tid & 7) * 4;
    const int n0 = bx * 32;
    const int i = by * 32 + iloc;
    const int srow = (n0 >= 128 ? 2048 : 0) + i;
    float4 f = *(const float4*)(f_e + (size_t)srow * 128 + ((n0 + nq) & 127));
    const float d = 1.0f / sqrtf((float)deg[i]);
    if (bx == 0 && (tid & 7) == 0) dinv[i] = d;
    T[nq + 0][iloc] = f.x * d; T[nq + 1][iloc] = f.y * d;
    T[nq + 2][iloc] = f.z * d; T[nq + 3][iloc] = f.w * d;
    __syncthreads();
    const int nloc = tid >> 3, ic = (tid & 7) * 4;
    unsigned short o[4];
#pragma unroll
    for (int c = 0; c < 4; ++c) o[c] = f2bf(T[nloc][ic + c]);
    *(ulonglong1*)(xt + (size_t)(n0 + nloc) * 2048 + by * 32 + ic) = *(ulonglong1*)o;
}

// ---------------- fused gram + NCE sums (+ optional topk rider block) ------
__launch_bounds__(256)
__global__ void k_nce_topk(const unsigned short* __restrict__ A,
                           const unsigned short* __restrict__ B,
                           float* __restrict__ rowsum, float* __restrict__ colsum,
                           float* __restrict__ pos, int gramBlocks, int bw,
                           const float* __restrict__ scores,
                           float* __restrict__ vals, int* __restrict__ idx)
{
    __shared__ unsigned short As[64][40];
    __shared__ unsigned short Bs[128][40];
    __shared__ float colbuf[4][128];
    __shared__ unsigned sv[2048];
    __shared__ int hist[256];
    __shared__ int shp, shr, sh_base, sh_out, wsum[5];
    const int tid = threadIdx.x;
    const int b = blockIdx.x;
    if (b < gramBlocks) {
        const int bx = b % bw, by = b / bw;
        const int i0 = by * 64;
        const int j0 = bx * 128;
        const int w = tid >> 6;
        const int lane = tid & 63;
        const int m = lane & 15;
        const int q = lane >> 4;
        f32x4 acc[8];
#pragma unroll
        for (int t = 0; t < 8; ++t)
#pragma unroll
            for (int r = 0; r < 4; ++r) acc[t][r] = 0.0f;
        const int ar = tid >> 2;
        const int ac = (tid & 3) * 8;
        for (int k = 0; k < 128; k += 32) {
            *(ulonglong2*)&As[ar][ac] =
                *(const ulonglong2*)(A + (size_t)(i0 + ar) * 128 + k + ac);
            *(ulonglong2*)&Bs[ar][ac] =
                *(const ulonglong2*)(B + (size_t)(j0 + ar) * 128 + k + ac);
            *(ulonglong2*)&Bs[ar + 64][ac] =
                *(const ulonglong2*)(B + (size_t)(j0 + ar + 64) * 128 + k + ac);
            __syncthreads();
            short8 a = *(const short8*)&As[w * 16 + m][q * 8];
#pragma unroll
            for (int nt = 0; nt < 8; ++nt) {
                short8 bb = *(const short8*)&Bs[nt * 16 + m][q * 8];
                acc[nt] = __builtin_amdgcn_mfma_f32_16x16x32_bf16(a, bb, acc[nt], 0, 0, 0);
            }
            __syncthreads();
        }
        float rpart[4] = {0.0f, 0.0f, 0.0f, 0.0f};
        float cpart[8];
#pragma unroll
        for (int nt = 0; nt < 8; ++nt) {
            const int col = j0 + nt * 16 + m;
            float cs = 0.0f;
#pragma unroll
            for (int r = 0; r < 4; ++r) {
                const int row = i0 + w * 16 + q * 4 + r;
                float g = acc[nt][r];
                float e = __expf(g * TINV);
                if (row == col) { pos[row] = g; e = 0.0f; }
                rpart[r] += e;
                cs += e;
            }
            cpart[nt] = cs;
        }
#pragma unroll
        for (int r = 0; r < 4; ++r) {
            float v = rpart[r];
            v += __shfl_xor(v, 1); v += __shfl_xor(v, 2);
            v += __shfl_xor(v, 4); v += __shfl_xor(v, 8);
            if (m == 0) atomicAdd(&rowsum[i0 + w * 16 + q * 4 + r], v);
        }
#pragma unroll
        for (int nt = 0; nt < 8; ++nt) {
            float v = cpart[nt];
            v += __shfl_xor(v, 16); v += __shfl_xor(v, 32);
            if (q == 0) colbuf[w][nt * 16 + m] = v;
        }
        __syncthreads();
        if (tid < 128) {
            float v = colbuf[0][tid] + colbuf[1][tid] + colbuf[2][tid] + colbuf[3][tid];
            atomicAdd(&colsum[j0 + tid], v);
        }
    } else {
        // ---- top-1024-of-2048 radix select, 256 threads ----
        for (int e = tid; e < 2048; e += 256) sv[e] = __float_as_uint(scores[e]);
        if (tid == 0) { shp = 0; shr = 1024; sh_base = 0; sh_out = 0; }
        __syncthreads();
        for (int byte = 3; byte >= 0; --byte) {
            hist[tid] = 0;
            __syncthreads();
            const unsigned pref = (unsigned)shp;
            const unsigned pmask = (byte == 3) ? 0u : (0xFFFFFFFFu << ((byte + 1) * 8));
            for (int e = tid; e < 2048; e += 256) {
                unsigned u = sv[e];
                if ((u & pmask) == (pref & pmask))
                    atomicAdd(&hist[(u >> (byte * 8)) & 255], 1);
            }
            __syncthreads();
            if (tid == 0) {
                int rem = shr, bs = 255;
                for (; bs > 0; --bs) {
                    if (hist[bs] >= rem) break;
                    rem -= hist[bs];
                }
                shp = (int)(pref | ((unsigned)bs << (byte * 8)));
                shr = rem;
            }
            __syncthreads();
        }
        const unsigned t = (unsigned)shp;
        const int remain = shr;
        const int lane = tid & 63, wave = tid >> 6;
        for (int pass = 0; pass < 8; ++pass) {
            const int e = pass * 256 + tid;
            const unsigned u = sv[e];
            const bool eq = (u == t);
            unsigned long long mk = __ballot(eq);
            int wpre = __popcll(mk & ((1ull << lane) - 1ull));
            if (lane == 0) wsum[wave] = __popcll(mk);
            __syncthreads();
            if (tid == 0) {
                int a = sh_base;
                for (int ww = 0; ww < 4; ++ww) { int c = wsum[ww]; wsum[ww] = a; a += c; }
                sh_base = a;
            }
            __syncthreads();
            const int rank = eq ? (wsum[wave] + wpre) : 0x7fffffff;
            if ((u > t) || (eq && rank < remain)) {
                int slot = atomicAdd(&sh_out, 1);
                idx[slot] = e;
                vals[slot] = __uint_as_float(u);
            }
            __syncthreads();
        }
    }
}

// ---------------- NCE finalize + build_ap (padded, R8) ---------------------
__global__ void k_final_ap(const float* __restrict__ rs, const float* __restrict__ cs,
                           const float* __restrict__ pos, float* __restrict__ out,
                           const unsigned long long* __restrict__ bits,
                           const int* __restrict__ idx,
                           unsigned short* __restrict__ Ap, int* __restrict__ degp)
{
    __shared__ unsigned long long pb[16][33];
    __shared__ unsigned long long qb[16][33];
    __shared__ float red[256];
    const int b = blockIdx.x;
    const int tid = threadIdx.x;
    if (b < 4096) {
        const int tp = (b >> 6) * 16;
        const int tq = (b & 63) * 16;
        for (int t = tid; t < 512; t += 256) {
            int r = t >> 5, w = t & 31;
            pb[r][w] = bits[(size_t)idx[tp + r] * 32 + w];
            qb[r][w] = bits[(size_t)idx[tq + r] * 32 + w];
        }
        __syncthreads();
        const int pi = tid >> 4, qi = tid & 15;
        unsigned long long acc = 0;
#pragma unroll
        for (int w = 0; w < 32; ++w) acc |= (pb[pi][w] & qb[qi][w]);
        Ap[(size_t)(tp + pi) * 1024 + tq + qi] =
            acc ? (unsigned short)0x3F80 : (unsigned short)0;
        int v = acc ? 1 : 0;
        v += __shfl_xor(v, 1); v += __shfl_xor(v, 2);
        v += __shfl_xor(v, 4); v += __shfl_xor(v, 8);
        if (qi == 0) atomicAdd(&degp[tp + pi], v);
    } else {
        const int i = (b - 4096) * 256 + tid;
        float p = pos[i] * TINV;
        float ep = __expf(p);
        float t = (logf(rs[i] + ep) - p) + (logf(cs[i] + ep) - p);
        red[tid] = t;
        __syncthreads();
        for (int s = 128; s > 0; s >>= 1) {
            if (tid < s) red[tid] += red[tid + s];
            __syncthreads();
        }
        if (tid == 0) atomicAdd(out, red[0] * (1.0f / 2048.0f));
    }
}

// ---------------- NCE finalize (pooled) ------------------------------------
__global__ void nce_final(const float* __restrict__ rs, const float* __restrict__ cs,
                          const float* __restrict__ pos, float invN,
                          float* __restrict__ out)
{
    const int i = blockIdx.x * 256 + threadIdx.x;
    float p = pos[i] * TINV;
    float ep = __expf(p);
    float t = (logf(rs[i] + ep) - p) + (logf(cs[i] + ep) - p);
    __shared__ float red[256];
    red[threadIdx.x] = t;
    __syncthreads();
    for (int s = 128; s > 0; s >>= 1) {
        if (threadIdx.x < s) red[threadIdx.x] += red[threadIdx.x + s];
        __syncthreads();
    }
    if (threadIdx.x == 0) atomicAdd(out, red[0] * invN);
}

// ------------- gather pooled features + build Xtp (+dinvp) -----------------
__global__ void gather_xt(const float* __restrict__ f_g, const int* __restrict__ idx,
                          const float* __restrict__ vals, const int* __restrict__ degp,
                          unsigned short* __restrict__ new_hb,
                          unsigned short* __restrict__ xtp, float* __restrict__ dinvp)
{
    __shared__ float T[32][33];
    const int b = blockIdx.x;                    // 256 = 8 x 32
    const int bx = b & 7, by = b >> 3;
    const int tid = threadIdx.x;                 // 256
    const int ploc = tid >> 3, nq = (tid & 7) * 4;
    const int n0 = bx * 32;
    const int p = by * 32 + ploc;
    const int s = idx[p];
    const float v = vals[p];
    const float dp = 1.0f / sqrtf((float)degp[p]);
    if (bx == 0 && (tid & 7) == 0) dinvp[p] = dp;
    const int srow = (n0 >= 128 ? 2048 : 0) + s;
    float4 f = *(const float4*)(f_g + (size_t)srow * 128 + ((n0 + nq) & 127));
    f.x *= v; f.y *= v; f.z *= v; f.w *= v;
    unsigned short o[4] = { f2bf(f.x), f2bf(f.y), f2bf(f.z), f2bf(f.w) };
    const int hrow = (n0 >= 128 ? 1024 : 0) + p;
    *(ulonglong1*)(new_hb + (size_t)hrow * 128 + ((n0 + nq) & 127)) = *(ulonglong1*)o;
    T[nq + 0][ploc] = f.x * dp; T[nq + 1][ploc] = f.y * dp;
    T[nq + 2][ploc] = f.z * dp; T[nq + 3][ploc] = f.w * dp;
    __syncthreads();
    const int nloc = tid >> 3, pc = (tid & 7) * 4;
    unsigned short o2[4];
#pragma unroll
    for (int c = 0; c < 4; ++c) o2[c] = f2bf(T[nloc][pc + c]);
    *(ulonglong1*)(xtp + (size_t)(n0 + nloc) * 1024 + by * 32 + pc) = *(ulonglong1*)o2;
}

// ---------------------------------------------------------------------------
extern "C" void kernel_launch(void* const* d_in, const int* in_sizes, int n_in,
                              void* d_out, int out_size, void* d_ws, size_t ws_size,
                              hipStream_t stream)
{
    (void)in_sizes; (void)n_in; (void)out_size; (void)ws_size;
    const float* fs      = (const float*)d_in[0];
    const float* ft      = (const float*)d_in[1];
    const float* W_embed = (const float*)d_in[2];
    const float* b_embed = (const float*)d_in[3];
    const float* W_gnn   = (const float*)d_in[4];
    const float* b_gnn   = (const float*)d_in[5];
    const float* W_pool  = (const float*)d_in[6];
    const float* b_pool  = (const float*)d_in[7];
    const float* W_gnnp  = (const float*)d_in[8];
    const float* b_gnnp  = (const float*)d_in[9];
    float* out = (float*)d_out;

    float* ws = (float*)d_ws;
    size_t o = 0;
    auto alloc = [&](size_t n) { float* p = ws + o; o += (n + 3) & ~3ull; return p; };
    float* bigB   = alloc(2048ull * 2048);       // embed/tag partials
    float* f_e    = alloc(4096 * 128);
    float* f_g    = alloc(4096 * 128);
    unsigned short* A01  = (unsigned short*)alloc(2048ull * 2048 / 2);
    unsigned short* febT = (unsigned short*)alloc(3ull * 4096 * 128 / 2);
    unsigned short* Xt1  = (unsigned short*)alloc(256ull * 2048 / 2);
    unsigned short* Xt2  = (unsigned short*)alloc(256ull * 2048 / 2);
    unsigned short* f_gb = (unsigned short*)alloc(4096ull * 128 / 2);
    unsigned short* Wtall= (unsigned short*)alloc(5ull * 16384 / 2);
    unsigned short* Ap01 = (unsigned short*)alloc(1024ull * 1024 / 2);
    unsigned short* nhb  = (unsigned short*)alloc(2ull * 2048 * 128 / 2);
    unsigned short* Xtp  = (unsigned short*)alloc(256ull * 1024 / 2);
    unsigned short* f_pb = (unsigned short*)alloc(2048ull * 128 / 2);
    float* dinv   = alloc(2048);
    float* scores = alloc(2048);
    float* vals   = alloc(1024);
    int*   idxb   = (int*)alloc(1024);
    float* dinvp  = alloc(1024);
    unsigned long long* bits = (unsigned long long*)alloc(2048 * 32 * 2);
    float* nceb = alloc(9216);
    int*   deg  = (int*)alloc(2048);
    int*   degp = (int*)alloc(1024);
    const int kZeroCount = 9216 + 2048 + 1024;   // 12288

    const size_t FSTR = 4096ull * 128;
    const size_t PSTR = 1024ull * 256;
    unsigned short* feb = febT;
    unsigned short* h1b = febT + FSTR;
    unsigned short* h2b = febT + 2 * FSTR;
    unsigned short* tmpb = nhb + 2048ull * 128;
    unsigned short* Wt  = Wtall;
    unsigned short* WtP = Wtall + 3ull * 16384;
    float* rs  = nceb;
    float* csu = nceb + 2048;
    float* pos = nceb + 4096;
    float* rsp  = nceb + 6144;
    float* csp  = nceb + 7168;
    float* posp = nceb + 8192;

    // 1. embed GEMM + zero control words + convert weights
    k_setup_embed<<<601, 256, 0, stream>>>(fs, ft, W_embed, bigB, FSTR,
                                           (int*)nceb, kZeroCount, out, W_gnn, W_gnnp, Wtall);
    // 2. embed combine + l2norm
    combine_norm<<<4096, 128, 0, stream>>>(bigB, 4, FSTR, b_embed, f_e, feb,
                                           nullptr, nullptr, nullptr);
    // 3. fused adjacency gram + threshold + pack + deg
    k_gram_fused<<<528, 256, 0, stream>>>(f_e, A01, bits, deg);
    // 4. Xt1 + dinv
    make_xt<<<512, 256, 0, stream>>>(f_e, deg, Xt1, dinv);
    // 5. hop1 full-K fused -> h1b + Xt2 (no reduce dispatch)
    k_hop<<<dim3(8, 32), 256, 0, stream>>>(A01, 2048, Xt1, 2048, 2048, 2048,
                                           dinv, h1b, Xt2);
    // 6. hop2 full-K fused -> h2b
    k_hop<<<dim3(8, 32), 256, 0, stream>>>(A01, 2048, Xt2, 2048, 2048, 2048,
                                           dinv, h2b, nullptr);
    // 7. TAG linear (batched z=3, M=4096)
    mm_bf16<<<dim3(1, 64, 3), 256, 0, stream>>>(feb, 128, FSTR, Wt, 128, 16384,
                                                bigB, 128, FSTR, 128, 0);
    // 8. TAG combine + l2norm + pooling scores
    combine_norm<<<4096, 128, 0, stream>>>(bigB, 3, FSTR, b_gnn, f_g, f_gb,
                                           W_pool, b_pool, scores);
    // 9. graph NCE gram + topk rider
    k_nce_topk<<<513, 256, 0, stream>>>(f_gb, f_gb + 2048 * 128, rs, csu, pos,
                                        512, 16, scores, vals, idxb);
    // 10. graph NCE finalize + pooled adjacency (Ap01 + degp)
    k_final_ap<<<4104, 256, 0, stream>>>(rs, csu, pos, out, bits, idxb, Ap01, degp);
    // 11. gather pooled features + Xtp + dinvp
    gather_xt<<<256, 256, 0, stream>>>(f_g, idxb, vals, degp, nhb, Xtp, dinvp);
    // 12. pooled hop full-K fused -> tmpb
    k_hop<<<dim3(8, 16), 256, 0, stream>>>(Ap01, 1024, Xtp, 1024, 1024, 1024,
                                           dinvp, tmpb, nullptr);
    // 13. pooled TAG linear (z=2, M=2048)
    mm_bf16<<<dim3(1, 32, 2), 256, 0, stream>>>(nhb, 128, 2048ull * 128, WtP, 128, 16384,
                                                bigB, 128, PSTR, 128, 0);
    // 14. pooled combine + l2norm (bf16 only)
    combine_norm<<<2048, 128, 0, stream>>>(bigB, 2, PSTR, b_gnnp, nullptr, f_pb,
                                           nullptr, nullptr, nullptr);
    // 15. pooled NCE gram
    k_nce_topk<<<128, 256, 0, stream>>>(f_pb, f_pb + 1024 * 128, rsp, csp, posp,
                                        128, 8, nullptr, nullptr, nullptr);
    // 16. pooled NCE finalize
    nce_final<<<4, 256, 0, stream>>>(rsp, csp, posp, 1.0f / 1024.0f, out);
}

// Round 13
// 215.922 us; speedup vs baseline: 1.2208x; 1.2208x over previous
//
#include <hip/hip_runtime.h>

// ---------------------------------------------------------------------------
// GNNLoss. N=2048, C=512, D=128, K_POOL=1024, T=0.07, NEG=-10.
// Round 13: exact R8 skeleton (227us best) + (a) hop split-K 8->4 (halved
// partial traffic, still 256 blocks), (b) pooled split-K 8->4, (c) final_ap
// 32x32 tiles (1024 blocks, halved bits traffic, packed stores). 19 dispatches.
// No cross-WG sync primitives (R6/R10: ~30us each on 8-XCD). N-tile >= 128
// in all hop/tag GEMMs (R12: narrow tiles multiply A traffic).
// ---------------------------------------------------------------------------

#define TINV (1.0f / 0.07f)

using short8 = __attribute__((ext_vector_type(8))) short;
using f32x4  = __attribute__((ext_vector_type(4))) float;

__device__ __forceinline__ unsigned short f2bf(float f) {
    unsigned u = __float_as_uint(f);
    u += 0x7fff + ((u >> 16) & 1);
    return (unsigned short)(u >> 16);
}

// ---------------- fp32 64x64 tile core -------------------------------------
template<bool BT>
__device__ __forceinline__ void mm_tile(const float* __restrict__ A, int lda,
                                        const float* __restrict__ B, int ldb,
                                        int i0, int j0, int k0, int k1,
                                        float (&acc)[4][4],
                                        float (&As)[16][68], float (&Bs)[16][68])
{
    const int tid = threadIdx.x;
    const int tx = tid & 15;
    const int ty = tid >> 4;
    const int lr = tid >> 2;
    const int lc = (tid & 3) * 4;
    for (int k = k0; k < k1; k += 16) {
        float4 av = *(const float4*)(A + (size_t)(i0 + lr) * lda + (k + lc));
        As[lc + 0][lr] = av.x; As[lc + 1][lr] = av.y;
        As[lc + 2][lr] = av.z; As[lc + 3][lr] = av.w;
        if (BT) {
            float4 bv = *(const float4*)(B + (size_t)(j0 + lr) * ldb + (k + lc));
            Bs[lc + 0][lr] = bv.x; Bs[lc + 1][lr] = bv.y;
            Bs[lc + 2][lr] = bv.z; Bs[lc + 3][lr] = bv.w;
        } else {
            const int n = tid & 63;
            const int kb = tid >> 6;
#pragma unroll
            for (int it = 0; it < 4; ++it)
                Bs[kb * 4 + it][n] = B[(size_t)(k + kb * 4 + it) * ldb + (j0 + n)];
        }
        __syncthreads();
#pragma unroll
        for (int kk = 0; kk < 16; ++kk) {
            float a[4], b[4];
#pragma unroll
            for (int u = 0; u < 4; ++u) a[u] = As[kk][ty * 4 + u];
#pragma unroll
            for (int v = 0; v < 4; ++v) b[v] = Bs[kk][tx * 4 + v];
#pragma unroll
            for (int u = 0; u < 4; ++u)
#pragma unroll
                for (int v = 0; v < 4; ++v)
                    acc[u][v] = fmaf(a[u], b[v], acc[u][v]);
        }
        __syncthreads();
    }
}

// ---------------- launch 1: embed GEMM + setup roles ----------------------
__launch_bounds__(256)
__global__ void k_setup_embed(const float* __restrict__ fs, const float* __restrict__ ft,
                              const float* __restrict__ W, float* __restrict__ part,
                              size_t zstr, int* __restrict__ zwords, int zcount,
                              float* __restrict__ out,
                              const float* __restrict__ Wg, const float* __restrict__ Wp,
                              unsigned short* __restrict__ Wtall)
{
    __shared__ float As[16][68];
    __shared__ float Bs[16][68];
    const int b = blockIdx.x;
    const int tid = threadIdx.x;
    if (b < 512) {
        const int z = b & 3;
        const int by = (b >> 2) & 63;
        const int bx = b >> 8;
        const float* A = (by < 32) ? ft : fs;
        const int i0 = (by & 31) * 64;
        const int j0 = bx * 64;
        float acc[4][4] = {};
        mm_tile<false>(A, 512, W, 128, i0, j0, z * 128, z * 128 + 128, acc, As, Bs);
        const int tx = tid & 15, ty = tid >> 4;
        float* dst = part + (size_t)z * zstr;
#pragma unroll
        for (int u = 0; u < 4; ++u) {
            const size_t ri = (size_t)(by * 64 + ty * 4 + u) * 128 + j0 + tx * 4;
#pragma unroll
            for (int v = 0; v < 4; ++v) dst[ri + v] = acc[u][v];
        }
    } else if (b < 561) {
        const int i = (b - 512) * 256 + tid;
        if (i < zcount) zwords[i] = 0;
        if (b == 512 && tid == 0) out[0] = 0.0f;
    } else {
        const int e0 = (b - 561) * 2048 + tid;
#pragma unroll
        for (int it = 0; it < 8; ++it) {
            const int e = e0 + it * 256;
            const int c = e >> 14;
            const int rem = e & 16383;
            const int n = rem >> 7, k = rem & 127;
            const float* src = (c < 3) ? (Wg + (size_t)c * 16384)
                                       : (Wp + (size_t)(c - 3) * 16384);
            Wtall[e] = f2bf(src[(size_t)k * 128 + n]);
        }
    }
}

// ---------------- fused gram + threshold + pack ----------------------------
__launch_bounds__(256)
__global__ void k_gram_fused(const float* __restrict__ f_e,
                             unsigned short* __restrict__ A01,
                             unsigned long long* __restrict__ bits,
                             int* __restrict__ deg)
{
    __shared__ float As[16][68];
    __shared__ float Bs[16][68];
    __shared__ unsigned char nib[64][16];
    __shared__ unsigned char nibT[64][16];
    __shared__ unsigned long long chk[64];
    __shared__ unsigned long long chkT[64];
    const int b = blockIdx.x;
    int by = (int)((sqrtf(8.0f * b + 1.0f) - 1.0f) * 0.5f);
    while ((by + 1) * (by + 2) / 2 <= b) ++by;
    while (by * (by + 1) / 2 > b) --by;
    const int bx = b - by * (by + 1) / 2;
    const int i0 = by * 64, j0 = bx * 64;
    float acc[4][4] = {};
    mm_tile<true>(f_e, 128, f_e, 128, i0, j0, 0, 128, acc, As, Bs);
    const int tid = threadIdx.x;
    const int tx = tid & 15, ty = tid >> 4;
    unsigned pb = 0;
#pragma unroll
    for (int u = 0; u < 4; ++u)
#pragma unroll
        for (int v = 0; v < 4; ++v) {
            bool pred = (acc[u][v] > 0.0f) || (i0 + ty * 4 + u == j0 + tx * 4 + v);
            pb |= (unsigned)pred << (u * 4 + v);
        }
#pragma unroll
    for (int u = 0; u < 4; ++u) nib[ty * 4 + u][tx] = (pb >> (4 * u)) & 15;
#pragma unroll
    for (int v = 0; v < 4; ++v) {
        unsigned nt = 0;
#pragma unroll
        for (int u = 0; u < 4; ++u) nt |= ((pb >> (u * 4 + v)) & 1u) << u;
        nibT[tx * 4 + v][ty] = nt;
    }
    __syncthreads();
    if (tid < 64) {
        unsigned long long c = 0;
#pragma unroll
        for (int t = 0; t < 16; ++t) c |= (unsigned long long)nib[tid][t] << (4 * t);
        chk[tid] = c;
        bits[(size_t)(i0 + tid) * 32 + (j0 >> 6)] = c;
        atomicAdd(&deg[i0 + tid], __popcll(c));
    } else if (tid < 128 && bx != by) {
        const int r = tid - 64;
        unsigned long long c = 0;
#pragma unroll
        for (int t = 0; t < 16; ++t) c |= (unsigned long long)nibT[r][t] << (4 * t);
        chkT[r] = c;
        bits[(size_t)(j0 + r) * 32 + (i0 >> 6)] = c;
        atomicAdd(&deg[j0 + r], __popcll(c));
    }
    __syncthreads();
#pragma unroll
    for (int it = 0; it < 16; ++it) {
        const int row = it * 4 + (tid >> 6);
        const int col = tid & 63;
        A01[(size_t)(i0 + row) * 2048 + j0 + col] =
            ((chk[row] >> col) & 1) ? (unsigned short)0x3F80 : (unsigned short)0;
        if (bx != by)
            A01[(size_t)(j0 + row) * 2048 + i0 + col] =
                ((chkT[row] >> col) & 1) ? (unsigned short)0x3F80 : (unsigned short)0;
    }
}

// ---------------- universal bf16 MFMA GEMM (plain store) -------------------
__launch_bounds__(256)
__global__ void mm_bf16(const unsigned short* __restrict__ A, int lda, size_t aZ,
                        const unsigned short* __restrict__ B, int ldb, size_t bZ,
                        float* __restrict__ C, int ldc, size_t cZ,
                        int Kc, int kZ)
{
    __shared__ unsigned short As[64][40];
    __shared__ unsigned short Bs[128][40];
    const int tid = threadIdx.x;
    const int bz = blockIdx.z;
    const int i0 = blockIdx.y * 64;
    const int j0 = blockIdx.x * 128;
    const int k0 = bz * kZ;
    const unsigned short* Ab = A + (size_t)bz * aZ;
    const unsigned short* Bb = B + (size_t)bz * bZ;
    float* Cb = C + (size_t)bz * cZ;
    const int w = tid >> 6;
    const int lane = tid & 63;
    const int m = lane & 15;
    const int q = lane >> 4;
    f32x4 acc[8];
#pragma unroll
    for (int t = 0; t < 8; ++t)
#pragma unroll
        for (int r = 0; r < 4; ++r) acc[t][r] = 0.0f;

    const int ar = tid >> 2;
    const int ac = (tid & 3) * 8;
    for (int ks = 0; ks < Kc; ks += 32) {
        const int k = k0 + ks;
        *(ulonglong2*)&As[ar][ac] =
            *(const ulonglong2*)(Ab + (size_t)(i0 + ar) * lda + k + ac);
        *(ulonglong2*)&Bs[ar][ac] =
            *(const ulonglong2*)(Bb + (size_t)(j0 + ar) * ldb + k + ac);
        *(ulonglong2*)&Bs[ar + 64][ac] =
            *(const ulonglong2*)(Bb + (size_t)(j0 + ar + 64) * ldb + k + ac);
        __syncthreads();
        short8 a = *(const short8*)&As[w * 16 + m][q * 8];
#pragma unroll
        for (int nt = 0; nt < 8; ++nt) {
            short8 b = *(const short8*)&Bs[nt * 16 + m][q * 8];
            acc[nt] = __builtin_amdgcn_mfma_f32_16x16x32_bf16(a, b, acc[nt], 0, 0, 0);
        }
        __syncthreads();
    }
#pragma unroll
    for (int nt = 0; nt < 8; ++nt) {
        const int col = j0 + nt * 16 + m;
#pragma unroll
        for (int r = 0; r < 4; ++r) {
            const int row = i0 + w * 16 + q * 4 + r;
            Cb[(size_t)row * ldc + col] = acc[nt][r];
        }
    }
}

// ------------- reduce split-K partials -> hb bf16 (+ optional Xt-next) -----
__global__ void reduce_hop(const float* __restrict__ part, int nz, size_t zstr,
                           int M, const float* __restrict__ dinv,
                           unsigned short* __restrict__ hb,
                           unsigned short* __restrict__ xt)
{
    __shared__ float T[32][33];
    const int tid = threadIdx.x;
    const int iloc = tid >> 3, nq = (tid & 7) * 4;
    const int n = blockIdx.x * 32 + nq;
    const int i = blockIdx.y * 32 + iloc;
    float4 s = *(const float4*)(part + (size_t)i * 256 + n);
    for (int z = 1; z < nz; ++z) {
        float4 t = *(const float4*)(part + (size_t)z * zstr + (size_t)i * 256 + n);
        s.x += t.x; s.y += t.y; s.z += t.z; s.w += t.w;
    }
    const float d = dinv[i];
    unsigned short o[4] = { f2bf(s.x * d), f2bf(s.y * d), f2bf(s.z * d), f2bf(s.w * d) };
    const int hrow = (n >= 128 ? M : 0) + i;
    *(ulonglong1*)(hb + (size_t)hrow * 128 + (n & 127)) = *(ulonglong1*)o;
    if (xt) {
        const float d2 = d * d;
        T[nq + 0][iloc] = s.x * d2; T[nq + 1][iloc] = s.y * d2;
        T[nq + 2][iloc] = s.z * d2; T[nq + 3][iloc] = s.w * d2;
        __syncthreads();
        const int nloc = tid >> 3, ic = (tid & 7) * 4;
        unsigned short o2[4];
#pragma unroll
        for (int c = 0; c < 4; ++c) o2[c] = f2bf(T[nloc][ic + c]);
        *(ulonglong1*)(xt + (size_t)(blockIdx.x * 32 + nloc) * M + blockIdx.y * 32 + ic) =
            *(ulonglong1*)o2;
    }
}

// ---------------- combine partials + bias + l2norm (+ optional score) ------
__global__ void combine_norm(const float* __restrict__ part, int nz, size_t zstr,
                             const float* __restrict__ bias,
                             float* __restrict__ f32out,
                             unsigned short* __restrict__ bf16out,
                             const float* __restrict__ Wp, const float* __restrict__ bp,
                             float* __restrict__ scores)
{
    const int row = blockIdx.x;
    const int tid = threadIdx.x;                 // 128
    float v = bias[tid];
    for (int z = 0; z < nz; ++z) v += part[(size_t)z * zstr + (size_t)row * 128 + tid];
    __shared__ float red[128];
    red[tid] = v * v;
    __syncthreads();
    for (int s = 64; s > 0; s >>= 1) {
        if (tid < s) red[tid] += red[tid + s];
        __syncthreads();
    }
    const float o = v * (1.0f / sqrtf(red[0]));
    if (f32out)  f32out[(size_t)row * 128 + tid] = o;
    if (bf16out) bf16out[(size_t)row * 128 + tid] = f2bf(o);
    if (scores && row < 2048) {
        __syncthreads();
        red[tid] = o * Wp[tid];
        __syncthreads();
        for (int s = 64; s > 0; s >>= 1) {
            if (tid < s) red[tid] += red[tid + s];
            __syncthreads();
        }
        if (tid == 0) scores[row] = 1.0f / (1.0f + expf(-(red[0] + bp[0])));
    }
}

// ------------- Xt1[n][i] = f_e[(branch)i][n&127] / sqrt(deg[i]) ------------
__global__ void make_xt(const float* __restrict__ f_e, const int* __restrict__ deg,
                        unsigned short* __restrict__ xt, float* __restrict__ dinv)
{
    __shared__ float T[32][33];
    const int b = blockIdx.x;                    // 512 = 8 x 64
    const int bx = b & 7, by = b >> 3;
    const int tid = threadIdx.x;                 // 256
    const int iloc = tid >> 3, nq = (tid & 7) * 4;
    const int n0 = bx * 32;
    const int i = by * 32 + iloc;
    const int srow = (n0 >= 128 ? 2048 : 0) + i;
    float4 f = *(const float4*)(f_e + (size_t)srow * 128 + ((n0 + nq) & 127));
    const float d = 1.0f / sqrtf((float)deg[i]);
    if (bx == 0 && (tid & 7) == 0) dinv[i] = d;
    T[nq + 0][iloc] = f.x * d; T[nq + 1][iloc] = f.y * d;
    T[nq + 2][iloc] = f.z * d; T[nq + 3][iloc] = f.w * d;
    __syncthreads();
    const int nloc = tid >> 3, ic = (tid & 7) * 4;
    unsigned short o[4];
#pragma unroll
    for (int c = 0; c < 4; ++c) o[c] = f2bf(T[nloc][ic + c]);
    *(ulonglong1*)(xt + (size_t)(n0 + nloc) * 2048 + by * 32 + ic) = *(ulonglong1*)o;
}

// ---------------- fused gram + NCE sums (+ optional topk rider block) ------
__launch_bounds__(256)
__global__ void k_nce_topk(const unsigned short* __restrict__ A,
                           const unsigned short* __restrict__ B,
                           float* __restrict__ rowsum, float* __restrict__ colsum,
                           float* __restrict__ pos, int gramBlocks, int bw,
                           const float* __restrict__ scores,
                           float* __restrict__ vals, int* __restrict__ idx)
{
    __shared__ unsigned short As[64][40];
    __shared__ unsigned short Bs[128][40];
    __shared__ float colbuf[4][128];
    __shared__ unsigned sv[2048];
    __shared__ int hist[256];
    __shared__ int shp, shr, sh_base, sh_out, wsum[5];
    const int tid = threadIdx.x;
    const int b = blockIdx.x;
    if (b < gramBlocks) {
        const int bx = b % bw, by = b / bw;
        const int i0 = by * 64;
        const int j0 = bx * 128;
        const int w = tid >> 6;
        const int lane = tid & 63;
        const int m = lane & 15;
        const int q = lane >> 4;
        f32x4 acc[8];
#pragma unroll
        for (int t = 0; t < 8; ++t)
#pragma unroll
            for (int r = 0; r < 4; ++r) acc[t][r] = 0.0f;
        const int ar = tid >> 2;
        const int ac = (tid & 3) * 8;
        for (int k = 0; k < 128; k += 32) {
            *(ulonglong2*)&As[ar][ac] =
                *(const ulonglong2*)(A + (size_t)(i0 + ar) * 128 + k + ac);
            *(ulonglong2*)&Bs[ar][ac] =
                *(const ulonglong2*)(B + (size_t)(j0 + ar) * 128 + k + ac);
            *(ulonglong2*)&Bs[ar + 64][ac] =
                *(const ulonglong2*)(B + (size_t)(j0 + ar + 64) * 128 + k + ac);
            __syncthreads();
            short8 a = *(const short8*)&As[w * 16 + m][q * 8];
#pragma unroll
            for (int nt = 0; nt < 8; ++nt) {
                short8 bb = *(const short8*)&Bs[nt * 16 + m][q * 8];
                acc[nt] = __builtin_amdgcn_mfma_f32_16x16x32_bf16(a, bb, acc[nt], 0, 0, 0);
            }
            __syncthreads();
        }
        float rpart[4] = {0.0f, 0.0f, 0.0f, 0.0f};
        float cpart[8];
#pragma unroll
        for (int nt = 0; nt < 8; ++nt) {
            const int col = j0 + nt * 16 + m;
            float cs = 0.0f;
#pragma unroll
            for (int r = 0; r < 4; ++r) {
                const int row = i0 + w * 16 + q * 4 + r;
                float g = acc[nt][r];
                float e = __expf(g * TINV);
                if (row == col) { pos[row] = g; e = 0.0f; }
                rpart[r] += e;
                cs += e;
            }
            cpart[nt] = cs;
        }
#pragma unroll
        for (int r = 0; r < 4; ++r) {
            float v = rpart[r];
            v += __shfl_xor(v, 1); v += __shfl_xor(v, 2);
            v += __shfl_xor(v, 4); v += __shfl_xor(v, 8);
            if (m == 0) atomicAdd(&rowsum[i0 + w * 16 + q * 4 + r], v);
        }
#pragma unroll
        for (int nt = 0; nt < 8; ++nt) {
            float v = cpart[nt];
            v += __shfl_xor(v, 16); v += __shfl_xor(v, 32);
            if (q == 0) colbuf[w][nt * 16 + m] = v;
        }
        __syncthreads();
        if (tid < 128) {
            float v = colbuf[0][tid] + colbuf[1][tid] + colbuf[2][tid] + colbuf[3][tid];
            atomicAdd(&colsum[j0 + tid], v);
        }
    } else {
        // ---- top-1024-of-2048 radix select, 256 threads ----
        for (int e = tid; e < 2048; e += 256) sv[e] = __float_as_uint(scores[e]);
        if (tid == 0) { shp = 0; shr = 1024; sh_base = 0; sh_out = 0; }
        __syncthreads();
        for (int byte = 3; byte >= 0; --byte) {
            hist[tid] = 0;
            __syncthreads();
            const unsigned pref = (unsigned)shp;
            const unsigned pmask = (byte == 3) ? 0u : (0xFFFFFFFFu << ((byte + 1) * 8));
            for (int e = tid; e < 2048; e += 256) {
                unsigned u = sv[e];
                if ((u & pmask) == (pref & pmask))
                    atomicAdd(&hist[(u >> (byte * 8)) & 255], 1);
            }
            __syncthreads();
            if (tid == 0) {
                int rem = shr, bs = 255;
                for (; bs > 0; --bs) {
                    if (hist[bs] >= rem) break;
                    rem -= hist[bs];
                }
                shp = (int)(pref | ((unsigned)bs << (byte * 8)));
                shr = rem;
            }
            __syncthreads();
        }
        const unsigned t = (unsigned)shp;
        const int remain = shr;
        const int lane = tid & 63, wave = tid >> 6;
        for (int pass = 0; pass < 8; ++pass) {
            const int e = pass * 256 + tid;
            const unsigned u = sv[e];
            const bool eq = (u == t);
            unsigned long long mk = __ballot(eq);
            int wpre = __popcll(mk & ((1ull << lane) - 1ull));
            if (lane == 0) wsum[wave] = __popcll(mk);
            __syncthreads();
            if (tid == 0) {
                int a = sh_base;
                for (int ww = 0; ww < 4; ++ww) { int c = wsum[ww]; wsum[ww] = a; a += c; }
                sh_base = a;
            }
            __syncthreads();
            const int rank = eq ? (wsum[wave] + wpre) : 0x7fffffff;
            if ((u > t) || (eq && rank < remain)) {
                int slot = atomicAdd(&sh_out, 1);
                idx[slot] = e;
                vals[slot] = __uint_as_float(u);
            }
            __syncthreads();
        }
    }
}

// ---------------- NCE finalize + build_ap (32x32 tiles) --------------------
// 1024 Ap tiles + 8 finalize blocks. pb/qb padded [32][33]; per-wave reads
// are 8-distinct-address broadcasts -> conflict-free. Packed 8B Ap stores.
__global__ void k_final_ap(const float* __restrict__ rs, const float* __restrict__ cs,
                           const float* __restrict__ pos, float* __restrict__ out,
                           const unsigned long long* __restrict__ bits,
                           const int* __restrict__ idx,
                           unsigned short* __restrict__ Ap, int* __restrict__ degp)
{
    __shared__ unsigned long long pb[32][33];
    __shared__ unsigned long long qb[32][33];
    __shared__ float red[256];
    const int b = blockIdx.x;
    const int tid = threadIdx.x;
    if (b < 1024) {
        const int tp = (b >> 5) * 32;
        const int tq = (b & 31) * 32;
        for (int t = tid; t < 1024; t += 256) {
            int r = t >> 5, w = t & 31;
            pb[r][w] = bits[(size_t)idx[tp + r] * 32 + w];
            qb[r][w] = bits[(size_t)idx[tq + r] * 32 + w];
        }
        __syncthreads();
        const int pi = tid >> 3;            // 0..31
        const int qc0 = (tid & 7) * 4;      // 0,4,..,28
        unsigned long long a0 = 0, a1 = 0, a2 = 0, a3 = 0;
#pragma unroll
        for (int w = 0; w < 32; ++w) {
            const unsigned long long p = pb[pi][w];
            a0 |= p & qb[qc0 + 0][w];
            a1 |= p & qb[qc0 + 1][w];
            a2 |= p & qb[qc0 + 2][w];
            a3 |= p & qb[qc0 + 3][w];
        }
        unsigned short o[4] = { (unsigned short)(a0 ? 0x3F80 : 0),
                                (unsigned short)(a1 ? 0x3F80 : 0),
                                (unsigned short)(a2 ? 0x3F80 : 0),
                                (unsigned short)(a3 ? 0x3F80 : 0) };
        *(ulonglong1*)&Ap[(size_t)(tp + pi) * 1024 + tq + qc0] = *(ulonglong1*)o;
        int v = (a0 ? 1 : 0) + (a1 ? 1 : 0) + (a2 ? 1 : 0) + (a3 ? 1 : 0);
        v += __shfl_xor(v, 1); v += __shfl_xor(v, 2); v += __shfl_xor(v, 4);
        if ((tid & 7) == 0) atomicAdd(&degp[tp + pi], v);
    } else {
        const int i = (b - 1024) * 256 + tid;
        float p = pos[i] * TINV;
        float ep = __expf(p);
        float t = (logf(rs[i] + ep) - p) + (logf(cs[i] + ep) - p);
        red[tid] = t;
        __syncthreads();
        for (int s = 128; s > 0; s >>= 1) {
            if (tid < s) red[tid] += red[tid + s];
            __syncthreads();
        }
        if (tid == 0) atomicAdd(out, red[0] * (1.0f / 2048.0f));
    }
}

// ---------------- NCE finalize (pooled) ------------------------------------
__global__ void nce_final(const float* __restrict__ rs, const float* __restrict__ cs,
                          const float* __restrict__ pos, float invN,
                          float* __restrict__ out)
{
    const int i = blockIdx.x * 256 + threadIdx.x;
    float p = pos[i] * TINV;
    float ep = __expf(p);
    float t = (logf(rs[i] + ep) - p) + (logf(cs[i] + ep) - p);
    __shared__ float red[256];
    red[threadIdx.x] = t;
    __syncthreads();
    for (int s = 128; s > 0; s >>= 1) {
        if (threadIdx.x < s) red[threadIdx.x] += red[threadIdx.x + s];
        __syncthreads();
    }
    if (threadIdx.x == 0) atomicAdd(out, red[0] * invN);
}

// ------------- gather pooled features + build Xtp (+dinvp) -----------------
__global__ void gather_xt(const float* __restrict__ f_g, const int* __restrict__ idx,
                          const float* __restrict__ vals, const int* __restrict__ degp,
                          unsigned short* __restrict__ new_hb,
                          unsigned short* __restrict__ xtp, float* __restrict__ dinvp)
{
    __shared__ float T[32][33];
    const int b = blockIdx.x;                    // 256 = 8 x 32
    const int bx = b & 7, by = b >> 3;
    const int tid = threadIdx.x;                 // 256
    const int ploc = tid >> 3, nq = (tid & 7) * 4;
    const int n0 = bx * 32;
    const int p = by * 32 + ploc;
    const int s = idx[p];
    const float v = vals[p];
    const float dp = 1.0f / sqrtf((float)degp[p]);
    if (bx == 0 && (tid & 7) == 0) dinvp[p] = dp;
    const int srow = (n0 >= 128 ? 2048 : 0) + s;
    float4 f = *(const float4*)(f_g + (size_t)srow * 128 + ((n0 + nq) & 127));
    f.x *= v; f.y *= v; f.z *= v; f.w *= v;
    unsigned short o[4] = { f2bf(f.x), f2bf(f.y), f2bf(f.z), f2bf(f.w) };
    const int hrow = (n0 >= 128 ? 1024 : 0) + p;
    *(ulonglong1*)(new_hb + (size_t)hrow * 128 + ((n0 + nq) & 127)) = *(ulonglong1*)o;
    T[nq + 0][ploc] = f.x * dp; T[nq + 1][ploc] = f.y * dp;
    T[nq + 2][ploc] = f.z * dp; T[nq + 3][ploc] = f.w * dp;
    __syncthreads();
    const int nloc = tid >> 3, pc = (tid & 7) * 4;
    unsigned short o2[4];
#pragma unroll
    for (int c = 0; c < 4; ++c) o2[c] = f2bf(T[nloc][pc + c]);
    *(ulonglong1*)(xtp + (size_t)(n0 + nloc) * 1024 + by * 32 + pc) = *(ulonglong1*)o2;
}

// ---------------------------------------------------------------------------
extern "C" void kernel_launch(void* const* d_in, const int* in_sizes, int n_in,
                              void* d_out, int out_size, void* d_ws, size_t ws_size,
                              hipStream_t stream)
{
    (void)in_sizes; (void)n_in; (void)out_size; (void)ws_size;
    const float* fs      = (const float*)d_in[0];
    const float* ft      = (const float*)d_in[1];
    const float* W_embed = (const float*)d_in[2];
    const float* b_embed = (const float*)d_in[3];
    const float* W_gnn   = (const float*)d_in[4];
    const float* b_gnn   = (const float*)d_in[5];
    const float* W_pool  = (const float*)d_in[6];
    const float* b_pool  = (const float*)d_in[7];
    const float* W_gnnp  = (const float*)d_in[8];
    const float* b_gnnp  = (const float*)d_in[9];
    float* out = (float*)d_out;

    float* ws = (float*)d_ws;
    size_t o = 0;
    auto alloc = [&](size_t n) { float* p = ws + o; o += (n + 3) & ~3ull; return p; };
    float* bigB   = alloc(2048ull * 2048);
    float* f_e    = alloc(4096 * 128);
    float* f_g    = alloc(4096 * 128);
    unsigned short* A01  = (unsigned short*)alloc(2048ull * 2048 / 2);
    unsigned short* febT = (unsigned short*)alloc(3ull * 4096 * 128 / 2);
    unsigned short* Xt1  = (unsigned short*)alloc(256ull * 2048 / 2);
    unsigned short* Xt2  = (unsigned short*)alloc(256ull * 2048 / 2);
    unsigned short* f_gb = (unsigned short*)alloc(4096ull * 128 / 2);
    unsigned short* Wtall= (unsigned short*)alloc(5ull * 16384 / 2);
    unsigned short* Ap01 = (unsigned short*)alloc(1024ull * 1024 / 2);
    unsigned short* nhb  = (unsigned short*)alloc(2ull * 2048 * 128 / 2);
    unsigned short* Xtp  = (unsigned short*)alloc(256ull * 1024 / 2);
    unsigned short* f_pb = (unsigned short*)alloc(2048ull * 128 / 2);
    float* dinv   = alloc(2048);
    float* scores = alloc(2048);
    float* vals   = alloc(1024);
    int*   idxb   = (int*)alloc(1024);
    float* dinvp  = alloc(1024);
    unsigned long long* bits = (unsigned long long*)alloc(2048 * 32 * 2);
    float* nceb = alloc(9216);
    int*   deg  = (int*)alloc(2048);
    int*   degp = (int*)alloc(1024);
    const int kZeroCount = 9216 + 2048 + 1024;   // 12288

    const size_t FSTR = 4096ull * 128;
    const size_t PSTR = 1024ull * 256;
    unsigned short* feb = febT;
    unsigned short* h1b = febT + FSTR;
    unsigned short* h2b = febT + 2 * FSTR;
    unsigned short* tmpb = nhb + 2048ull * 128;
    unsigned short* Wt  = Wtall;
    unsigned short* WtP = Wtall + 3ull * 16384;
    float* rs  = nceb;
    float* csu = nceb + 2048;
    float* pos = nceb + 4096;
    float* rsp  = nceb + 6144;
    float* csp  = nceb + 7168;
    float* posp = nceb + 8192;

    // 1. embed GEMM + zero control words + convert weights
    k_setup_embed<<<601, 256, 0, stream>>>(fs, ft, W_embed, bigB, FSTR,
                                           (int*)nceb, kZeroCount, out, W_gnn, W_gnnp, Wtall);
    // 2. embed combine + l2norm
    combine_norm<<<4096, 128, 0, stream>>>(bigB, 4, FSTR, b_embed, f_e, feb,
                                           nullptr, nullptr, nullptr);
    // 3. fused adjacency gram + threshold + pack + deg
    k_gram_fused<<<528, 256, 0, stream>>>(f_e, A01, bits, deg);
    // 4. Xt1 + dinv
    make_xt<<<512, 256, 0, stream>>>(f_e, deg, Xt1, dinv);
    // 5/6. hop1 (split-K 4, 256 blocks) + reduce -> h1b + Xt2
    mm_bf16<<<dim3(2, 32, 4), 256, 0, stream>>>(A01, 2048, 0, Xt1, 2048, 0,
                                                bigB, 256, FSTR, 512, 512);
    reduce_hop<<<dim3(8, 64), 256, 0, stream>>>(bigB, 4, FSTR, 2048, dinv, h1b, Xt2);
    // 7/8. hop2 + reduce -> h2b
    mm_bf16<<<dim3(2, 32, 4), 256, 0, stream>>>(A01, 2048, 0, Xt2, 2048, 0,
                                                bigB, 256, FSTR, 512, 512);
    reduce_hop<<<dim3(8, 64), 256, 0, stream>>>(bigB, 4, FSTR, 2048, dinv, h2b, nullptr);
    // 9. TAG linear (batched z=3, M=4096)
    mm_bf16<<<dim3(1, 64, 3), 256, 0, stream>>>(feb, 128, FSTR, Wt, 128, 16384,
                                                bigB, 128, FSTR, 128, 0);
    // 10. TAG combine + l2norm + pooling scores
    combine_norm<<<4096, 128, 0, stream>>>(bigB, 3, FSTR, b_gnn, f_g, f_gb,
                                           W_pool, b_pool, scores);
    // 11. graph NCE gram + topk rider
    k_nce_topk<<<513, 256, 0, stream>>>(f_gb, f_gb + 2048 * 128, rs, csu, pos,
                                        512, 16, scores, vals, idxb);
    // 12. graph NCE finalize + pooled adjacency (32x32 tiles)
    k_final_ap<<<1032, 256, 0, stream>>>(rs, csu, pos, out, bits, idxb, Ap01, degp);
    // 13. gather pooled features + Xtp + dinvp
    gather_xt<<<256, 256, 0, stream>>>(f_g, idxb, vals, degp, nhb, Xtp, dinvp);
    // 14/15. pooled hop (split-K 4) + reduce -> tmpb
    mm_bf16<<<dim3(2, 16, 4), 256, 0, stream>>>(Ap01, 1024, 0, Xtp, 1024, 0,
                                                bigB, 256, PSTR, 256, 256);
    reduce_hop<<<dim3(8, 32), 256, 0, stream>>>(bigB, 4, PSTR, 1024, dinvp, tmpb, nullptr);
    // 16. pooled TAG linear (z=2, M=2048)
    mm_bf16<<<dim3(1, 32, 2), 256, 0, stream>>>(nhb, 128, 2048ull * 128, WtP, 128, 16384,
                                                bigB, 128, PSTR, 128, 0);
    // 17. pooled combine + l2norm (bf16 only)
    combine_norm<<<2048, 128, 0, stream>>>(bigB, 2, PSTR, b_gnnp, nullptr, f_pb,
                                           nullptr, nullptr, nullptr);
    // 18. pooled NCE gram
    k_nce_topk<<<128, 256, 0, stream>>>(f_pb, f_pb + 1024 * 128, rsp, csp, posp,
                                        128, 8, nullptr, nullptr, nullptr);
    // 19. pooled NCE finalize
    nce_final<<<4, 256, 0, stream>>>(rsp, csp, posp, 1.0f / 1024.0f, out);
}

// Round 14
// 214.633 us; speedup vs baseline: 1.2281x; 1.0060x over previous
//
#include <hip/hip_runtime.h>

// ---------------------------------------------------------------------------
// GNNLoss. N=2048, C=512, D=128, K_POOL=1024, T=0.07, NEG=-10.
// Round 14: R13 (215.9us) + vectorized store paths: packed 8B A01 stores in
// k_gram_fused (was 2B scalar), float4 partial stores in k_setup_embed.
// 19 dispatches. Rules kept: no cross-WG sync (R6/R10 ~30us/barrier);
// N-tile >= 128 in hop/tag GEMMs (R12); fusion only at >=256 blocks (R11).
// ---------------------------------------------------------------------------

#define TINV (1.0f / 0.07f)

using short8 = __attribute__((ext_vector_type(8))) short;
using f32x4  = __attribute__((ext_vector_type(4))) float;

__device__ __forceinline__ unsigned short f2bf(float f) {
    unsigned u = __float_as_uint(f);
    u += 0x7fff + ((u >> 16) & 1);
    return (unsigned short)(u >> 16);
}

// ---------------- fp32 64x64 tile core -------------------------------------
template<bool BT>
__device__ __forceinline__ void mm_tile(const float* __restrict__ A, int lda,
                                        const float* __restrict__ B, int ldb,
                                        int i0, int j0, int k0, int k1,
                                        float (&acc)[4][4],
                                        float (&As)[16][68], float (&Bs)[16][68])
{
    const int tid = threadIdx.x;
    const int tx = tid & 15;
    const int ty = tid >> 4;
    const int lr = tid >> 2;
    const int lc = (tid & 3) * 4;
    for (int k = k0; k < k1; k += 16) {
        float4 av = *(const float4*)(A + (size_t)(i0 + lr) * lda + (k + lc));
        As[lc + 0][lr] = av.x; As[lc + 1][lr] = av.y;
        As[lc + 2][lr] = av.z; As[lc + 3][lr] = av.w;
        if (BT) {
            float4 bv = *(const float4*)(B + (size_t)(j0 + lr) * ldb + (k + lc));
            Bs[lc + 0][lr] = bv.x; Bs[lc + 1][lr] = bv.y;
            Bs[lc + 2][lr] = bv.z; Bs[lc + 3][lr] = bv.w;
        } else {
            const int n = tid & 63;
            const int kb = tid >> 6;
#pragma unroll
            for (int it = 0; it < 4; ++it)
                Bs[kb * 4 + it][n] = B[(size_t)(k + kb * 4 + it) * ldb + (j0 + n)];
        }
        __syncthreads();
#pragma unroll
        for (int kk = 0; kk < 16; ++kk) {
            float a[4], b[4];
#pragma unroll
            for (int u = 0; u < 4; ++u) a[u] = As[kk][ty * 4 + u];
#pragma unroll
            for (int v = 0; v < 4; ++v) b[v] = Bs[kk][tx * 4 + v];
#pragma unroll
            for (int u = 0; u < 4; ++u)
#pragma unroll
                for (int v = 0; v < 4; ++v)
                    acc[u][v] = fmaf(a[u], b[v], acc[u][v]);
        }
        __syncthreads();
    }
}

// ---------------- launch 1: embed GEMM + setup roles ----------------------
__launch_bounds__(256)
__global__ void k_setup_embed(const float* __restrict__ fs, const float* __restrict__ ft,
                              const float* __restrict__ W, float* __restrict__ part,
                              size_t zstr, int* __restrict__ zwords, int zcount,
                              float* __restrict__ out,
                              const float* __restrict__ Wg, const float* __restrict__ Wp,
                              unsigned short* __restrict__ Wtall)
{
    __shared__ float As[16][68];
    __shared__ float Bs[16][68];
    const int b = blockIdx.x;
    const int tid = threadIdx.x;
    if (b < 512) {
        const int z = b & 3;
        const int by = (b >> 2) & 63;
        const int bx = b >> 8;
        const float* A = (by < 32) ? ft : fs;
        const int i0 = (by & 31) * 64;
        const int j0 = bx * 64;
        float acc[4][4] = {};
        mm_tile<false>(A, 512, W, 128, i0, j0, z * 128, z * 128 + 128, acc, As, Bs);
        const int tx = tid & 15, ty = tid >> 4;
        float* dst = part + (size_t)z * zstr;
#pragma unroll
        for (int u = 0; u < 4; ++u) {
            const size_t ri = (size_t)(by * 64 + ty * 4 + u) * 128 + j0 + tx * 4;
            float4 vv;
            vv.x = acc[u][0]; vv.y = acc[u][1]; vv.z = acc[u][2]; vv.w = acc[u][3];
            *(float4*)(dst + ri) = vv;
        }
    } else if (b < 561) {
        const int i = (b - 512) * 256 + tid;
        if (i < zcount) zwords[i] = 0;
        if (b == 512 && tid == 0) out[0] = 0.0f;
    } else {
        const int e0 = (b - 561) * 2048 + tid;
#pragma unroll
        for (int it = 0; it < 8; ++it) {
            const int e = e0 + it * 256;
            const int c = e >> 14;
            const int rem = e & 16383;
            const int n = rem >> 7, k = rem & 127;
            const float* src = (c < 3) ? (Wg + (size_t)c * 16384)
                                       : (Wp + (size_t)(c - 3) * 16384);
            Wtall[e] = f2bf(src[(size_t)k * 128 + n]);
        }
    }
}

// ---------------- fused gram + threshold + pack (8B A01 stores) ------------
__launch_bounds__(256)
__global__ void k_gram_fused(const float* __restrict__ f_e,
                             unsigned short* __restrict__ A01,
                             unsigned long long* __restrict__ bits,
                             int* __restrict__ deg)
{
    __shared__ float As[16][68];
    __shared__ float Bs[16][68];
    __shared__ unsigned char nib[64][16];
    __shared__ unsigned char nibT[64][16];
    __shared__ unsigned long long chk[64];
    __shared__ unsigned long long chkT[64];
    const int b = blockIdx.x;
    int by = (int)((sqrtf(8.0f * b + 1.0f) - 1.0f) * 0.5f);
    while ((by + 1) * (by + 2) / 2 <= b) ++by;
    while (by * (by + 1) / 2 > b) --by;
    const int bx = b - by * (by + 1) / 2;
    const int i0 = by * 64, j0 = bx * 64;
    float acc[4][4] = {};
    mm_tile<true>(f_e, 128, f_e, 128, i0, j0, 0, 128, acc, As, Bs);
    const int tid = threadIdx.x;
    const int tx = tid & 15, ty = tid >> 4;
    unsigned pb = 0;
#pragma unroll
    for (int u = 0; u < 4; ++u)
#pragma unroll
        for (int v = 0; v < 4; ++v) {
            bool pred = (acc[u][v] > 0.0f) || (i0 + ty * 4 + u == j0 + tx * 4 + v);
            pb |= (unsigned)pred << (u * 4 + v);
        }
#pragma unroll
    for (int u = 0; u < 4; ++u) nib[ty * 4 + u][tx] = (pb >> (4 * u)) & 15;
#pragma unroll
    for (int v = 0; v < 4; ++v) {
        unsigned nt = 0;
#pragma unroll
        for (int u = 0; u < 4; ++u) nt |= ((pb >> (u * 4 + v)) & 1u) << u;
        nibT[tx * 4 + v][ty] = nt;
    }
    __syncthreads();
    if (tid < 64) {
        unsigned long long c = 0;
#pragma unroll
        for (int t = 0; t < 16; ++t) c |= (unsigned long long)nib[tid][t] << (4 * t);
        chk[tid] = c;
        bits[(size_t)(i0 + tid) * 32 + (j0 >> 6)] = c;
        atomicAdd(&deg[i0 + tid], __popcll(c));
    } else if (tid < 128 && bx != by) {
        const int r = tid - 64;
        unsigned long long c = 0;
#pragma unroll
        for (int t = 0; t < 16; ++t) c |= (unsigned long long)nibT[r][t] << (4 * t);
        chkT[r] = c;
        bits[(size_t)(j0 + r) * 32 + (i0 >> 6)] = c;
        atomicAdd(&deg[j0 + r], __popcll(c));
    }
    __syncthreads();
    // packed 8B stores: 4 iters x (16 rows x 16 col-groups of 4)
#pragma unroll
    for (int it = 0; it < 4; ++it) {
        const int row = it * 16 + (tid >> 4);
        const int c0 = (tid & 15) * 4;
        unsigned short o[4];
#pragma unroll
        for (int c = 0; c < 4; ++c)
            o[c] = ((chk[row] >> (c0 + c)) & 1) ? (unsigned short)0x3F80 : (unsigned short)0;
        *(ulonglong1*)&A01[(size_t)(i0 + row) * 2048 + j0 + c0] = *(ulonglong1*)o;
        if (bx != by) {
            unsigned short o2[4];
#pragma unroll
            for (int c = 0; c < 4; ++c)
                o2[c] = ((chkT[row] >> (c0 + c)) & 1) ? (unsigned short)0x3F80 : (unsigned short)0;
            *(ulonglong1*)&A01[(size_t)(j0 + row) * 2048 + i0 + c0] = *(ulonglong1*)o2;
        }
    }
}

// ---------------- universal bf16 MFMA GEMM (plain store) -------------------
__launch_bounds__(256)
__global__ void mm_bf16(const unsigned short* __restrict__ A, int lda, size_t aZ,
                        const unsigned short* __restrict__ B, int ldb, size_t bZ,
                        float* __restrict__ C, int ldc, size_t cZ,
                        int Kc, int kZ)
{
    __shared__ unsigned short As[64][40];
    __shared__ unsigned short Bs[128][40];
    const int tid = threadIdx.x;
    const int bz = blockIdx.z;
    const int i0 = blockIdx.y * 64;
    const int j0 = blockIdx.x * 128;
    const int k0 = bz * kZ;
    const unsigned short* Ab = A + (size_t)bz * aZ;
    const unsigned short* Bb = B + (size_t)bz * bZ;
    float* Cb = C + (size_t)bz * cZ;
    const int w = tid >> 6;
    const int lane = tid & 63;
    const int m = lane & 15;
    const int q = lane >> 4;
    f32x4 acc[8];
#pragma unroll
    for (int t = 0; t < 8; ++t)
#pragma unroll
        for (int r = 0; r < 4; ++r) acc[t][r] = 0.0f;

    const int ar = tid >> 2;
    const int ac = (tid & 3) * 8;
    for (int ks = 0; ks < Kc; ks += 32) {
        const int k = k0 + ks;
        *(ulonglong2*)&As[ar][ac] =
            *(const ulonglong2*)(Ab + (size_t)(i0 + ar) * lda + k + ac);
        *(ulonglong2*)&Bs[ar][ac] =
            *(const ulonglong2*)(Bb + (size_t)(j0 + ar) * ldb + k + ac);
        *(ulonglong2*)&Bs[ar + 64][ac] =
            *(const ulonglong2*)(Bb + (size_t)(j0 + ar + 64) * ldb + k + ac);
        __syncthreads();
        short8 a = *(const short8*)&As[w * 16 + m][q * 8];
#pragma unroll
        for (int nt = 0; nt < 8; ++nt) {
            short8 b = *(const short8*)&Bs[nt * 16 + m][q * 8];
            acc[nt] = __builtin_amdgcn_mfma_f32_16x16x32_bf16(a, b, acc[nt], 0, 0, 0);
        }
        __syncthreads();
    }
#pragma unroll
    for (int nt = 0; nt < 8; ++nt) {
        const int col = j0 + nt * 16 + m;
#pragma unroll
        for (int r = 0; r < 4; ++r) {
            const int row = i0 + w * 16 + q * 4 + r;
            Cb[(size_t)row * ldc + col] = acc[nt][r];
        }
    }
}

// ------------- reduce split-K partials -> hb bf16 (+ optional Xt-next) -----
__global__ void reduce_hop(const float* __restrict__ part, int nz, size_t zstr,
                           int M, const float* __restrict__ dinv,
                           unsigned short* __restrict__ hb,
                           unsigned short* __restrict__ xt)
{
    __shared__ float T[32][33];
    const int tid = threadIdx.x;
    const int iloc = tid >> 3, nq = (tid & 7) * 4;
    const int n = blockIdx.x * 32 + nq;
    const int i = blockIdx.y * 32 + iloc;
    float4 s = *(const float4*)(part + (size_t)i * 256 + n);
    for (int z = 1; z < nz; ++z) {
        float4 t = *(const float4*)(part + (size_t)z * zstr + (size_t)i * 256 + n);
        s.x += t.x; s.y += t.y; s.z += t.z; s.w += t.w;
    }
    const float d = dinv[i];
    unsigned short o[4] = { f2bf(s.x * d), f2bf(s.y * d), f2bf(s.z * d), f2bf(s.w * d) };
    const int hrow = (n >= 128 ? M : 0) + i;
    *(ulonglong1*)(hb + (size_t)hrow * 128 + (n & 127)) = *(ulonglong1*)o;
    if (xt) {
        const float d2 = d * d;
        T[nq + 0][iloc] = s.x * d2; T[nq + 1][iloc] = s.y * d2;
        T[nq + 2][iloc] = s.z * d2; T[nq + 3][iloc] = s.w * d2;
        __syncthreads();
        const int nloc = tid >> 3, ic = (tid & 7) * 4;
        unsigned short o2[4];
#pragma unroll
        for (int c = 0; c < 4; ++c) o2[c] = f2bf(T[nloc][ic + c]);
        *(ulonglong1*)(xt + (size_t)(blockIdx.x * 32 + nloc) * M + blockIdx.y * 32 + ic) =
            *(ulonglong1*)o2;
    }
}

// ---------------- combine partials + bias + l2norm (+ optional score) ------
__global__ void combine_norm(const float* __restrict__ part, int nz, size_t zstr,
                             const float* __restrict__ bias,
                             float* __restrict__ f32out,
                             unsigned short* __restrict__ bf16out,
                             const float* __restrict__ Wp, const float* __restrict__ bp,
                             float* __restrict__ scores)
{
    const int row = blockIdx.x;
    const int tid = threadIdx.x;                 // 128
    float v = bias[tid];
    for (int z = 0; z < nz; ++z) v += part[(size_t)z * zstr + (size_t)row * 128 + tid];
    __shared__ float red[128];
    red[tid] = v * v;
    __syncthreads();
    for (int s = 64; s > 0; s >>= 1) {
        if (tid < s) red[tid] += red[tid + s];
        __syncthreads();
    }
    const float o = v * (1.0f / sqrtf(red[0]));
    if (f32out)  f32out[(size_t)row * 128 + tid] = o;
    if (bf16out) bf16out[(size_t)row * 128 + tid] = f2bf(o);
    if (scores && row < 2048) {
        __syncthreads();
        red[tid] = o * Wp[tid];
        __syncthreads();
        for (int s = 64; s > 0; s >>= 1) {
            if (tid < s) red[tid] += red[tid + s];
            __syncthreads();
        }
        if (tid == 0) scores[row] = 1.0f / (1.0f + expf(-(red[0] + bp[0])));
    }
}

// ------------- Xt1[n][i] = f_e[(branch)i][n&127] / sqrt(deg[i]) ------------
__global__ void make_xt(const float* __restrict__ f_e, const int* __restrict__ deg,
                        unsigned short* __restrict__ xt, float* __restrict__ dinv)
{
    __shared__ float T[32][33];
    const int b = blockIdx.x;                    // 512 = 8 x 64
    const int bx = b & 7, by = b >> 3;
    const int tid = threadIdx.x;                 // 256
    const int iloc = tid >> 3, nq = (tid & 7) * 4;
    const int n0 = bx * 32;
    const int i = by * 32 + iloc;
    const int srow = (n0 >= 128 ? 2048 : 0) + i;
    float4 f = *(const float4*)(f_e + (size_t)srow * 128 + ((n0 + nq) & 127));
    const float d = 1.0f / sqrtf((float)deg[i]);
    if (bx == 0 && (tid & 7) == 0) dinv[i] = d;
    T[nq + 0][iloc] = f.x * d; T[nq + 1][iloc] = f.y * d;
    T[nq + 2][iloc] = f.z * d; T[nq + 3][iloc] = f.w * d;
    __syncthreads();
    const int nloc = tid >> 3, ic = (tid & 7) * 4;
    unsigned short o[4];
#pragma unroll
    for (int c = 0; c < 4; ++c) o[c] = f2bf(T[nloc][ic + c]);
    *(ulonglong1*)(xt + (size_t)(n0 + nloc) * 2048 + by * 32 + ic) = *(ulonglong1*)o;
}

// ---------------- fused gram + NCE sums (+ optional topk rider block) ------
__launch_bounds__(256)
__global__ void k_nce_topk(const unsigned short* __restrict__ A,
                           const unsigned short* __restrict__ B,
                           float* __restrict__ rowsum, float* __restrict__ colsum,
                           float* __restrict__ pos, int gramBlocks, int bw,
                           const float* __restrict__ scores,
                           float* __restrict__ vals, int* __restrict__ idx)
{
    __shared__ unsigned short As[64][40];
    __shared__ unsigned short Bs[128][40];
    __shared__ float colbuf[4][128];
    __shared__ unsigned sv[2048];
    __shared__ int hist[256];
    __shared__ int shp, shr, sh_base, sh_out, wsum[5];
    const int tid = threadIdx.x;
    const int b = blockIdx.x;
    if (b < gramBlocks) {
        const int bx = b % bw, by = b / bw;
        const int i0 = by * 64;
        const int j0 = bx * 128;
        const int w = tid >> 6;
        const int lane = tid & 63;
        const int m = lane & 15;
        const int q = lane >> 4;
        f32x4 acc[8];
#pragma unroll
        for (int t = 0; t < 8; ++t)
#pragma unroll
            for (int r = 0; r < 4; ++r) acc[t][r] = 0.0f;
        const int ar = tid >> 2;
        const int ac = (tid & 3) * 8;
        for (int k = 0; k < 128; k += 32) {
            *(ulonglong2*)&As[ar][ac] =
                *(const ulonglong2*)(A + (size_t)(i0 + ar) * 128 + k + ac);
            *(ulonglong2*)&Bs[ar][ac] =
                *(const ulonglong2*)(B + (size_t)(j0 + ar) * 128 + k + ac);
            *(ulonglong2*)&Bs[ar + 64][ac] =
                *(const ulonglong2*)(B + (size_t)(j0 + ar + 64) * 128 + k + ac);
            __syncthreads();
            short8 a = *(const short8*)&As[w * 16 + m][q * 8];
#pragma unroll
            for (int nt = 0; nt < 8; ++nt) {
                short8 bb = *(const short8*)&Bs[nt * 16 + m][q * 8];
                acc[nt] = __builtin_amdgcn_mfma_f32_16x16x32_bf16(a, bb, acc[nt], 0, 0, 0);
            }
            __syncthreads();
        }
        float rpart[4] = {0.0f, 0.0f, 0.0f, 0.0f};
        float cpart[8];
#pragma unroll
        for (int nt = 0; nt < 8; ++nt) {
            const int col = j0 + nt * 16 + m;
            float cs = 0.0f;
#pragma unroll
            for (int r = 0; r < 4; ++r) {
                const int row = i0 + w * 16 + q * 4 + r;
                float g = acc[nt][r];
                float e = __expf(g * TINV);
                if (row == col) { pos[row] = g; e = 0.0f; }
                rpart[r] += e;
                cs += e;
            }
            cpart[nt] = cs;
        }
#pragma unroll
        for (int r = 0; r < 4; ++r) {
            float v = rpart[r];
            v += __shfl_xor(v, 1); v += __shfl_xor(v, 2);
            v += __shfl_xor(v, 4); v += __shfl_xor(v, 8);
            if (m == 0) atomicAdd(&rowsum[i0 + w * 16 + q * 4 + r], v);
        }
#pragma unroll
        for (int nt = 0; nt < 8; ++nt) {
            float v = cpart[nt];
            v += __shfl_xor(v, 16); v += __shfl_xor(v, 32);
            if (q == 0) colbuf[w][nt * 16 + m] = v;
        }
        __syncthreads();
        if (tid < 128) {
            float v = colbuf[0][tid] + colbuf[1][tid] + colbuf[2][tid] + colbuf[3][tid];
            atomicAdd(&colsum[j0 + tid], v);
        }
    } else {
        // ---- top-1024-of-2048 radix select, 256 threads ----
        for (int e = tid; e < 2048; e += 256) sv[e] = __float_as_uint(scores[e]);
        if (tid == 0) { shp = 0; shr = 1024; sh_base = 0; sh_out = 0; }
        __syncthreads();
        for (int byte = 3; byte >= 0; --byte) {
            hist[tid] = 0;
            __syncthreads();
            const unsigned pref = (unsigned)shp;
            const unsigned pmask = (byte == 3) ? 0u : (0xFFFFFFFFu << ((byte + 1) * 8));
            for (int e = tid; e < 2048; e += 256) {
                unsigned u = sv[e];
                if ((u & pmask) == (pref & pmask))
                    atomicAdd(&hist[(u >> (byte * 8)) & 255], 1);
            }
            __syncthreads();
            if (tid == 0) {
                int rem = shr, bs = 255;
                for (; bs > 0; --bs) {
                    if (hist[bs] >= rem) break;
                    rem -= hist[bs];
                }
                shp = (int)(pref | ((unsigned)bs << (byte * 8)));
                shr = rem;
            }
            __syncthreads();
        }
        const unsigned t = (unsigned)shp;
        const int remain = shr;
        const int lane = tid & 63, wave = tid >> 6;
        for (int pass = 0; pass < 8; ++pass) {
            const int e = pass * 256 + tid;
            const unsigned u = sv[e];
            const bool eq = (u == t);
            unsigned long long mk = __ballot(eq);
            int wpre = __popcll(mk & ((1ull << lane) - 1ull));
            if (lane == 0) wsum[wave] = __popcll(mk);
            __syncthreads();
            if (tid == 0) {
                int a = sh_base;
                for (int ww = 0; ww < 4; ++ww) { int c = wsum[ww]; wsum[ww] = a; a += c; }
                sh_base = a;
            }
            __syncthreads();
            const int rank = eq ? (wsum[wave] + wpre) : 0x7fffffff;
            if ((u > t) || (eq && rank < remain)) {
                int slot = atomicAdd(&sh_out, 1);
                idx[slot] = e;
                vals[slot] = __uint_as_float(u);
            }
            __syncthreads();
        }
    }
}

// ---------------- NCE finalize + build_ap (32x32 tiles, R13) ---------------
__global__ void k_final_ap(const float* __restrict__ rs, const float* __restrict__ cs,
                           const float* __restrict__ pos, float* __restrict__ out,
                           const unsigned long long* __restrict__ bits,
                           const int* __restrict__ idx,
                           unsigned short* __restrict__ Ap, int* __restrict__ degp)
{
    __shared__ unsigned long long pb[32][33];
    __shared__ unsigned long long qb[32][33];
    __shared__ float red[256];
    const int b = blockIdx.x;
    const int tid = threadIdx.x;
    if (b < 1024) {
        const int tp = (b >> 5) * 32;
        const int tq = (b & 31) * 32;
        for (int t = tid; t < 1024; t += 256) {
            int r = t >> 5, w = t & 31;
            pb[r][w] = bits[(size_t)idx[tp + r] * 32 + w];
            qb[r][w] = bits[(size_t)idx[tq + r] * 32 + w];
        }
        __syncthreads();
        const int pi = tid >> 3;            // 0..31
        const int qc0 = (tid & 7) * 4;      // 0,4,..,28
        unsigned long long a0 = 0, a1 = 0, a2 = 0, a3 = 0;
#pragma unroll
        for (int w = 0; w < 32; ++w) {
            const unsigned long long p = pb[pi][w];
            a0 |= p & qb[qc0 + 0][w];
            a1 |= p & qb[qc0 + 1][w];
            a2 |= p & qb[qc0 + 2][w];
            a3 |= p & qb[qc0 + 3][w];
        }
        unsigned short o[4] = { (unsigned short)(a0 ? 0x3F80 : 0),
                                (unsigned short)(a1 ? 0x3F80 : 0),
                                (unsigned short)(a2 ? 0x3F80 : 0),
                                (unsigned short)(a3 ? 0x3F80 : 0) };
        *(ulonglong1*)&Ap[(size_t)(tp + pi) * 1024 + tq + qc0] = *(ulonglong1*)o;
        int v = (a0 ? 1 : 0) + (a1 ? 1 : 0) + (a2 ? 1 : 0) + (a3 ? 1 : 0);
        v += __shfl_xor(v, 1); v += __shfl_xor(v, 2); v += __shfl_xor(v, 4);
        if ((tid & 7) == 0) atomicAdd(&degp[tp + pi], v);
    } else {
        const int i = (b - 1024) * 256 + tid;
        float p = pos[i] * TINV;
        float ep = __expf(p);
        float t = (logf(rs[i] + ep) - p) + (logf(cs[i] + ep) - p);
        red[tid] = t;
        __syncthreads();
        for (int s = 128; s > 0; s >>= 1) {
            if (tid < s) red[tid] += red[tid + s];
            __syncthreads();
        }
        if (tid == 0) atomicAdd(out, red[0] * (1.0f / 2048.0f));
    }
}

// ---------------- NCE finalize (pooled) ------------------------------------
__global__ void nce_final(const float* __restrict__ rs, const float* __restrict__ cs,
                          const float* __restrict__ pos, float invN,
                          float* __restrict__ out)
{
    const int i = blockIdx.x * 256 + threadIdx.x;
    float p = pos[i] * TINV;
    float ep = __expf(p);
    float t = (logf(rs[i] + ep) - p) + (logf(cs[i] + ep) - p);
    __shared__ float red[256];
    red[threadIdx.x] = t;
    __syncthreads();
    for (int s = 128; s > 0; s >>= 1) {
        if (threadIdx.x < s) red[threadIdx.x] += red[threadIdx.x + s];
        __syncthreads();
    }
    if (threadIdx.x == 0) atomicAdd(out, red[0] * invN);
}

// ------------- gather pooled features + build Xtp (+dinvp) -----------------
__global__ void gather_xt(const float* __restrict__ f_g, const int* __restrict__ idx,
                          const float* __restrict__ vals, const int* __restrict__ degp,
                          unsigned short* __restrict__ new_hb,
                          unsigned short* __restrict__ xtp, float* __restrict__ dinvp)
{
    __shared__ float T[32][33];
    const int b = blockIdx.x;                    // 256 = 8 x 32
    const int bx = b & 7, by = b >> 3;
    const int tid = threadIdx.x;                 // 256
    const int ploc = tid >> 3, nq = (tid & 7) * 4;
    const int n0 = bx * 32;
    const int p = by * 32 + ploc;
    const int s = idx[p];
    const float v = vals[p];
    const float dp = 1.0f / sqrtf((float)degp[p]);
    if (bx == 0 && (tid & 7) == 0) dinvp[p] = dp;
    const int srow = (n0 >= 128 ? 2048 : 0) + s;
    float4 f = *(const float4*)(f_g + (size_t)srow * 128 + ((n0 + nq) & 127));
    f.x *= v; f.y *= v; f.z *= v; f.w *= v;
    unsigned short o[4] = { f2bf(f.x), f2bf(f.y), f2bf(f.z), f2bf(f.w) };
    const int hrow = (n0 >= 128 ? 1024 : 0) + p;
    *(ulonglong1*)(new_hb + (size_t)hrow * 128 + ((n0 + nq) & 127)) = *(ulonglong1*)o;
    T[nq + 0][ploc] = f.x * dp; T[nq + 1][ploc] = f.y * dp;
    T[nq + 2][ploc] = f.z * dp; T[nq + 3][ploc] = f.w * dp;
    __syncthreads();
    const int nloc = tid >> 3, pc = (tid & 7) * 4;
    unsigned short o2[4];
#pragma unroll
    for (int c = 0; c < 4; ++c) o2[c] = f2bf(T[nloc][pc + c]);
    *(ulonglong1*)(xtp + (size_t)(n0 + nloc) * 1024 + by * 32 + pc) = *(ulonglong1*)o2;
}

// ---------------------------------------------------------------------------
extern "C" void kernel_launch(void* const* d_in, const int* in_sizes, int n_in,
                              void* d_out, int out_size, void* d_ws, size_t ws_size,
                              hipStream_t stream)
{
    (void)in_sizes; (void)n_in; (void)out_size; (void)ws_size;
    const float* fs      = (const float*)d_in[0];
    const float* ft      = (const float*)d_in[1];
    const float* W_embed = (const float*)d_in[2];
    const float* b_embed = (const float*)d_in[3];
    const float* W_gnn   = (const float*)d_in[4];
    const float* b_gnn   = (const float*)d_in[5];
    const float* W_pool  = (const float*)d_in[6];
    const float* b_pool  = (const float*)d_in[7];
    const float* W_gnnp  = (const float*)d_in[8];
    const float* b_gnnp  = (const float*)d_in[9];
    float* out = (float*)d_out;

    float* ws = (float*)d_ws;
    size_t o = 0;
    auto alloc = [&](size_t n) { float* p = ws + o; o += (n + 3) & ~3ull; return p; };
    float* bigB   = alloc(2048ull * 2048);
    float* f_e    = alloc(4096 * 128);
    float* f_g    = alloc(4096 * 128);
    unsigned short* A01  = (unsigned short*)alloc(2048ull * 2048 / 2);
    unsigned short* febT = (unsigned short*)alloc(3ull * 4096 * 128 / 2);
    unsigned short* Xt1  = (unsigned short*)alloc(256ull * 2048 / 2);
    unsigned short* Xt2  = (unsigned short*)alloc(256ull * 2048 / 2);
    unsigned short* f_gb = (unsigned short*)alloc(4096ull * 128 / 2);
    unsigned short* Wtall= (unsigned short*)alloc(5ull * 16384 / 2);
    unsigned short* Ap01 = (unsigned short*)alloc(1024ull * 1024 / 2);
    unsigned short* nhb  = (unsigned short*)alloc(2ull * 2048 * 128 / 2);
    unsigned short* Xtp  = (unsigned short*)alloc(256ull * 1024 / 2);
    unsigned short* f_pb = (unsigned short*)alloc(2048ull * 128 / 2);
    float* dinv   = alloc(2048);
    float* scores = alloc(2048);
    float* vals   = alloc(1024);
    int*   idxb   = (int*)alloc(1024);
    float* dinvp  = alloc(1024);
    unsigned long long* bits = (unsigned long long*)alloc(2048 * 32 * 2);
    float* nceb = alloc(9216);
    int*   deg  = (int*)alloc(2048);
    int*   degp = (int*)alloc(1024);
    const int kZeroCount = 9216 + 2048 + 1024;   // 12288

    const size_t FSTR = 4096ull * 128;
    const size_t PSTR = 1024ull * 256;
    unsigned short* feb = febT;
    unsigned short* h1b = febT + FSTR;
    unsigned short* h2b = febT + 2 * FSTR;
    unsigned short* tmpb = nhb + 2048ull * 128;
    unsigned short* Wt  = Wtall;
    unsigned short* WtP = Wtall + 3ull * 16384;
    float* rs  = nceb;
    float* csu = nceb + 2048;
    float* pos = nceb + 4096;
    float* rsp  = nceb + 6144;
    float* csp  = nceb + 7168;
    float* posp = nceb + 8192;

    // 1. embed GEMM + zero control words + convert weights
    k_setup_embed<<<601, 256, 0, stream>>>(fs, ft, W_embed, bigB, FSTR,
                                           (int*)nceb, kZeroCount, out, W_gnn, W_gnnp, Wtall);
    // 2. embed combine + l2norm
    combine_norm<<<4096, 128, 0, stream>>>(bigB, 4, FSTR, b_embed, f_e, feb,
                                           nullptr, nullptr, nullptr);
    // 3. fused adjacency gram + threshold + pack + deg
    k_gram_fused<<<528, 256, 0, stream>>>(f_e, A01, bits, deg);
    // 4. Xt1 + dinv
    make_xt<<<512, 256, 0, stream>>>(f_e, deg, Xt1, dinv);
    // 5/6. hop1 (split-K 4, 256 blocks) + reduce -> h1b + Xt2
    mm_bf16<<<dim3(2, 32, 4), 256, 0, stream>>>(A01, 2048, 0, Xt1, 2048, 0,
                                                bigB, 256, FSTR, 512, 512);
    reduce_hop<<<dim3(8, 64), 256, 0, stream>>>(bigB, 4, FSTR, 2048, dinv, h1b, Xt2);
    // 7/8. hop2 + reduce -> h2b
    mm_bf16<<<dim3(2, 32, 4), 256, 0, stream>>>(A01, 2048, 0, Xt2, 2048, 0,
                                                bigB, 256, FSTR, 512, 512);
    reduce_hop<<<dim3(8, 64), 256, 0, stream>>>(bigB, 4, FSTR, 2048, dinv, h2b, nullptr);
    // 9. TAG linear (batched z=3, M=4096)
    mm_bf16<<<dim3(1, 64, 3), 256, 0, stream>>>(feb, 128, FSTR, Wt, 128, 16384,
                                                bigB, 128, FSTR, 128, 0);
    // 10. TAG combine + l2norm + pooling scores
    combine_norm<<<4096, 128, 0, stream>>>(bigB, 3, FSTR, b_gnn, f_g, f_gb,
                                           W_pool, b_pool, scores);
    // 11. graph NCE gram + topk rider
    k_nce_topk<<<513, 256, 0, stream>>>(f_gb, f_gb + 2048 * 128, rs, csu, pos,
                                        512, 16, scores, vals, idxb);
    // 12. graph NCE finalize + pooled adjacency (32x32 tiles)
    k_final_ap<<<1032, 256, 0, stream>>>(rs, csu, pos, out, bits, idxb, Ap01, degp);
    // 13. gather pooled features + Xtp + dinvp
    gather_xt<<<256, 256, 0, stream>>>(f_g, idxb, vals, degp, nhb, Xtp, dinvp);
    // 14/15. pooled hop (split-K 4) + reduce -> tmpb
    mm_bf16<<<dim3(2, 16, 4), 256, 0, stream>>>(Ap01, 1024, 0, Xtp, 1024, 0,
                                                bigB, 256, PSTR, 256, 256);
    reduce_hop<<<dim3(8, 32), 256, 0, stream>>>(bigB, 4, PSTR, 1024, dinvp, tmpb, nullptr);
    // 16. pooled TAG linear (z=2, M=2048)
    mm_bf16<<<dim3(1, 32, 2), 256, 0, stream>>>(nhb, 128, 2048ull * 128, WtP, 128, 16384,
                                                bigB, 128, PSTR, 128, 0);
    // 17. pooled combine + l2norm (bf16 only)
    combine_norm<<<2048, 128, 0, stream>>>(bigB, 2, PSTR, b_gnnp, nullptr, f_pb,
                                           nullptr, nullptr, nullptr);
    // 18. pooled NCE gram
    k_nce_topk<<<128, 256, 0, stream>>>(f_pb, f_pb + 1024 * 128, rsp, csp, posp,
                                        128, 8, nullptr, nullptr, nullptr);
    // 19. pooled NCE finalize
    nce_final<<<4, 256, 0, stream>>>(rsp, csp, posp, 1.0f / 1024.0f, out);
}